// Round 10
// baseline (307.786 us; speedup 1.0000x reference)
//
#include <hip/hip_runtime.h>
#include <hip/hip_bf16.h>
#include <cstdint>
#include <cstddef>

typedef unsigned short u16;
typedef unsigned int u32;
typedef __attribute__((ext_vector_type(8))) short short8v;   // 8 bf16 MFMA frag
typedef __attribute__((ext_vector_type(4))) float f32x4;     // MFMA accumulator
typedef __attribute__((ext_vector_type(4))) u16 u16x4;
typedef __attribute__((ext_vector_type(8))) u16 u16x8;

// Problem constants
static constexpr int Bc = 2, Tc = 2048, Dc = 1024, Hc = 16, HKVc = 4, HDc = 64;
static constexpr int Mc = Bc * Tc;                 // 4096 rows
static constexpr float EPSc = 1.1920929e-07f;

static __device__ __forceinline__ u16 f2bf(float f) {
  u32 u = __builtin_bit_cast(u32, f);
  return (u16)((u + 0x7fffu + ((u >> 16) & 1u)) >> 16);
}
static __device__ __forceinline__ float bf2f(u16 b) {
  u32 u = ((u32)b) << 16;
  return __builtin_bit_cast(float, u);
}
static __device__ __forceinline__ float fast_exp2(float x) {
  float r;
  asm("v_exp_f32 %0, %1" : "=v"(r) : "v"(x));
  return r;
}
static __device__ __forceinline__ u32 cvt_pk_bf16(float lo, float hi) {
  u32 r;
  asm("v_cvt_pk_bf16_f32 %0, %1, %2" : "=v"(r) : "v"(lo), "v"(hi));
  return r;
}

// ---------------- numpy-exact fp32 pairwise abs-mean (verified round 3/7) ----------------
__global__ __launch_bounds__(256) void np_leafsum_all(const float* __restrict__ q_w,
                                                      const float* __restrict__ k_w,
                                                      const float* __restrict__ o_w,
                                                      float* __restrict__ leaf) {
  int blk = blockIdx.x;
  const float* w;
  float* out;
  int lfbase;
  if (blk < 256)      { w = q_w; out = leaf;         lfbase = blk * 32; }
  else if (blk < 320) { w = k_w; out = leaf + 8192;  lfbase = (blk - 256) * 32; }
  else                { w = o_w; out = leaf + 10240; lfbase = (blk - 320) * 32; }
  int t = threadIdx.x;
  int lf = lfbase + (t >> 3), j = t & 7;
  const float* a = w + (size_t)lf * 128;
  float r = fabsf(a[j]);
#pragma unroll
  for (int i = 8; i < 128; i += 8) r += fabsf(a[i + j]);
  float x = r + __shfl_xor(r, 1);
  float y = x + __shfl_xor(x, 2);
  float z = y + __shfl_xor(y, 4);
  if (j == 0) out[lf] = z;
}

__global__ __launch_bounds__(256) void np_treemean3(const float* __restrict__ leaf,
                                                    float* __restrict__ th) {
  int m = blockIdx.x;
  const float* src = leaf + (m == 0 ? 0 : (m == 1 ? 8192 : 10240));
  int nle = (m == 1) ? 2048 : 8192;
  float inv_n = (m == 1) ? (1.0f / 262144.0f) : (1.0f / 1048576.0f);
  int t = threadIdx.x;
  int chunk = nle >> 8;                      // 32 or 8, power of two
  float v[32];
  for (int i = 0; i < chunk; i += 4) {
    float4 f = *(const float4*)&src[t * chunk + i];
    v[i] = f.x; v[i + 1] = f.y; v[i + 2] = f.z; v[i + 3] = f.w;
  }
  for (int cnt = chunk >> 1; cnt >= 1; cnt >>= 1)
    for (int i = 0; i < cnt; ++i) v[i] = v[2 * i] + v[2 * i + 1];
  float s = v[0];
#pragma unroll
  for (int off = 1; off < 64; off <<= 1) s += __shfl_xor(s, off);
  __shared__ float red[4];
  if ((t & 63) == 0) red[t >> 6] = s;
  __syncthreads();
  if (t == 0) th[m] = ((red[0] + red[1]) + (red[2] + red[3])) * inv_n;
}

// ---------------- fused: ternary quantize (q/k/o) + v_w hi/lo split ----------------
__global__ __launch_bounds__(256) void quant_split_all(const float* __restrict__ q_w,
                                                       const float* __restrict__ k_w,
                                                       const float* __restrict__ o_w,
                                                       const float* __restrict__ v_w,
                                                       const float* __restrict__ th,
                                                       u16* __restrict__ Wq,
                                                       u16* __restrict__ Wk,
                                                       u16* __restrict__ Wo,
                                                       u16* __restrict__ Vwh,
                                                       u16* __restrict__ Vwl) {
  int i4 = blockIdx.x * 256 + threadIdx.x;   // float4 index
  if (i4 < 589824) {
    const float* w; u16* o; float t;
    int j;
    if (i4 < 262144)      { w = q_w; o = Wq; t = th[0]; j = i4; }
    else if (i4 < 327680) { w = k_w; o = Wk; t = th[1]; j = i4 - 262144; }
    else                  { w = o_w; o = Wo; t = th[2]; j = i4 - 327680; }
    float4 v = *(const float4*)&w[(size_t)j * 4];
    float y[4] = {v.x, v.y, v.z, v.w};
    u16x4 q;
#pragma unroll
    for (int c = 0; c < 4; ++c)
      q[c] = (y[c] > t) ? (u16)0x3F80 : ((y[c] < -t) ? (u16)0xBF80 : (u16)0);
    *(u16x4*)&o[(size_t)j * 4] = q;
  } else {
    int j = i4 - 589824;                     // v_w float4 index, [0, 65536)
    float4 v = *(const float4*)&v_w[(size_t)j * 4];
    float y[4] = {v.x, v.y, v.z, v.w};
    u16x4 h, l;
#pragma unroll
    for (int c = 0; c < 4; ++c) {
      u16 hb = f2bf(y[c]);
      h[c] = hb;
      l[c] = f2bf(y[c] - bf2f(hb));
    }
    *(u16x4*)&Vwh[(size_t)j * 4] = h;
    *(u16x4*)&Vwl[(size_t)j * 4] = l;
  }
}

// ---------------- RMSNorm -> bf16 hi/lo (2 gains) + raw-x hi/lo split ----------------
__global__ __launch_bounds__(256) void rmsnorm_split6(const float* __restrict__ X,
                                                      const float* __restrict__ g1,
                                                      const float* __restrict__ g2,
                                                      u16* __restrict__ H1, u16* __restrict__ L1,
                                                      u16* __restrict__ H2, u16* __restrict__ L2,
                                                      u16* __restrict__ HV, u16* __restrict__ LV) {
  int row = blockIdx.x;
  const float* xr = X + (size_t)row * Dc;
  int tid = threadIdx.x;
  float4 v = *(const float4*)&xr[tid * 4];
  float vv[4] = {v.x, v.y, v.z, v.w};
  if (HV != nullptr) {           // raw x split for the V path
    u16x4 h, l;
#pragma unroll
    for (int j = 0; j < 4; ++j) {
      u16 hb = f2bf(vv[j]);
      h[j] = hb;
      l[j] = f2bf(vv[j] - bf2f(hb));
    }
    *(u16x4*)&HV[(size_t)row * Dc + tid * 4] = h;
    *(u16x4*)&LV[(size_t)row * Dc + tid * 4] = l;
  }
  float ss = v.x * v.x + v.y * v.y + v.z * v.z + v.w * v.w;
#pragma unroll
  for (int off = 1; off < 64; off <<= 1) ss += __shfl_xor(ss, off);
  __shared__ float red[4];
  if ((tid & 63) == 0) red[tid >> 6] = ss;
  __syncthreads();
  float tot = red[0] + red[1] + red[2] + red[3];
  float inv = 1.0f / sqrtf(tot * (1.0f / (float)Dc) + EPSc);
  {
    float4 a = *(const float4*)&g1[tid * 4];
    float ga[4] = {a.x, a.y, a.z, a.w};
    u16x4 h, l;
#pragma unroll
    for (int j = 0; j < 4; ++j) {
      float y = vv[j] * inv * ga[j];
      u16 hb = f2bf(y);
      h[j] = hb;
      l[j] = f2bf(y - bf2f(hb));
    }
    *(u16x4*)&H1[(size_t)row * Dc + tid * 4] = h;
    *(u16x4*)&L1[(size_t)row * Dc + tid * 4] = l;
  }
  if (g2 != nullptr) {
    float4 a = *(const float4*)&g2[tid * 4];
    float ga[4] = {a.x, a.y, a.z, a.w};
    u16x4 h, l;
#pragma unroll
    for (int j = 0; j < 4; ++j) {
      float y = vv[j] * inv * ga[j];
      u16 hb = f2bf(y);
      h[j] = hb;
      l[j] = f2bf(y - bf2f(hb));
    }
    *(u16x4*)&H2[(size_t)row * Dc + tid * 4] = h;
    *(u16x4*)&L2[(size_t)row * Dc + tid * 4] = l;
  }
}

// ---------------- bf16 MFMA GEMM, templated tile ----------------
// MODE 0: C fp32.  MODE 1: O1/O2 = bf16 hi/lo.  MODE 3: O1 = bf16, cols permuted
// within each 32-block by gp(k) = (k&~31) | ((k>>2)&3)<<3 | ((k>>4)&1)<<2 | (k&3)
// (matches attn's in-register P slot order for the swapped-PV MFMA; verified r9).
template <bool PB, int MODE, int MF, int NF>
__global__ __launch_bounds__(256, 1) void gemm_mfma(
    const u16* __restrict__ Ah, const u16* __restrict__ Al,
    const u16* __restrict__ Bh, const u16* __restrict__ Bl,
    int M, int N, int K,
    float* __restrict__ C, u16* __restrict__ O1, u16* __restrict__ O2) {
  constexpr int BM = MF * 32, BN = NF * 32;
  constexpr int APT = BM / 32;               // u16x8 loads per thread for A tile
  constexpr int BPT = BN / 32;
  __shared__ __align__(16) u16 AhS[BM * 64], AlS[BM * 64];
  __shared__ __align__(16) u16 BhS[BN * 64];
  __shared__ __align__(16) u16 BlS[PB ? BN * 64 : 8];
  int tid = threadIdx.x;
  int l = tid & 63, w = tid >> 6;
  int wm = (w >> 1) * (BM / 2), wn = (w & 1) * (BN / 2);
  int bm = blockIdx.y * BM, bn = blockIdx.x * BN;
  u16x8 rAh[APT], rAl[APT], rBh[BPT], rBl[PB ? BPT : 1];
  f32x4 acc[MF][NF] = {};
#define LOADTILE(kb_)                                                               \
  {                                                                                 \
    _Pragma("unroll") for (int p = 0; p < APT; ++p) {                               \
      int idx = tid + p * 256;                                                      \
      int row = idx >> 3, cc = idx & 7;                                             \
      rAh[p] = *(const u16x8*)&Ah[(size_t)(bm + row) * K + (kb_) + cc * 8];         \
      rAl[p] = *(const u16x8*)&Al[(size_t)(bm + row) * K + (kb_) + cc * 8];         \
    }                                                                               \
    _Pragma("unroll") for (int p = 0; p < BPT; ++p) {                               \
      int idx = tid + p * 256;                                                      \
      int row = idx >> 3, cc = idx & 7;                                             \
      rBh[p] = *(const u16x8*)&Bh[(size_t)(bn + row) * K + (kb_) + cc * 8];         \
      if (PB) rBl[p] = *(const u16x8*)&Bl[(size_t)(bn + row) * K + (kb_) + cc * 8]; \
    }                                                                               \
  }
  LOADTILE(0)
  for (int kb = 0; kb < K; kb += 64) {
    __syncthreads();
#pragma unroll
    for (int p = 0; p < APT; ++p) {
      int idx = tid + p * 256;
      int row = idx >> 3, cc = idx & 7;
      int off = row * 64 + ((cc * 8) ^ ((row & 7) << 3));
      *(u16x8*)&AhS[off] = rAh[p];
      *(u16x8*)&AlS[off] = rAl[p];
    }
#pragma unroll
    for (int p = 0; p < BPT; ++p) {
      int idx = tid + p * 256;
      int row = idx >> 3, cc = idx & 7;
      int off = row * 64 + ((cc * 8) ^ ((row & 7) << 3));
      *(u16x8*)&BhS[off] = rBh[p];
      if (PB) *(u16x8*)&BlS[off] = rBl[p];
    }
    if (kb + 64 < K) LOADTILE(kb + 64)
    __syncthreads();
    __builtin_amdgcn_s_setprio(1);
#pragma unroll
    for (int sl = 0; sl < 2; ++sl) {
      short8v fa[MF], fal[MF], fb[NF], fbl[NF];
      int kof = (l >> 4) * 8 + sl * 32;
#pragma unroll
      for (int m = 0; m < MF; ++m) {
        int row = wm + m * 16 + (l & 15);
        int off = row * 64 + (kof ^ ((row & 7) << 3));
        fa[m] = *(const short8v*)&AhS[off];
        fal[m] = *(const short8v*)&AlS[off];
      }
#pragma unroll
      for (int n = 0; n < NF; ++n) {
        int row = wn + n * 16 + (l & 15);
        int off = row * 64 + (kof ^ ((row & 7) << 3));
        fb[n] = *(const short8v*)&BhS[off];
        if (PB) fbl[n] = *(const short8v*)&BlS[off];
      }
#pragma unroll
      for (int m = 0; m < MF; ++m)
#pragma unroll
        for (int n = 0; n < NF; ++n) {
          acc[m][n] = __builtin_amdgcn_mfma_f32_16x16x32_bf16(fa[m], fb[n], acc[m][n], 0, 0, 0);
          acc[m][n] = __builtin_amdgcn_mfma_f32_16x16x32_bf16(fal[m], fb[n], acc[m][n], 0, 0, 0);
          if (PB)
            acc[m][n] = __builtin_amdgcn_mfma_f32_16x16x32_bf16(fa[m], fbl[n], acc[m][n], 0, 0, 0);
        }
    }
    __builtin_amdgcn_s_setprio(0);
  }
#undef LOADTILE
#pragma unroll
  for (int m = 0; m < MF; ++m)
#pragma unroll
    for (int n = 0; n < NF; ++n)
#pragma unroll
      for (int r = 0; r < 4; ++r) {
        int grow = bm + wm + m * 16 + (l >> 4) * 4 + r;
        int gcol = bn + wn + n * 16 + (l & 15);
        float v = acc[m][n][r];
        if (MODE == 0) {
          C[(size_t)grow * N + gcol] = v;
        } else if (MODE == 1) {
          u16 hb = f2bf(v);
          O1[(size_t)grow * N + gcol] = hb;
          O2[(size_t)grow * N + gcol] = f2bf(v - bf2f(hb));
        } else {
          int k = gcol & 31;
          int gp = (gcol & ~31) | (((k >> 2) & 3) << 3) |
                   (((k >> 4) & 1) << 2) | (k & 3);
          O1[(size_t)grow * N + gp] = f2bf(v);
        }
      }
}

// ---------------- MFMA causal GQA attention v5 (swapped, TK=64, 24KB LDS) ----------------
// Grid (32, H, B), qt = 31 - bx (largest first), nsteps = qt+1. 24KB -> 6 blocks/CU.
// s = mfma(K, Q): lane holds S[key][q=l&15]; softmax lane-local + 2 shfl.
// PV = mfma(Vt, P-in-register). Oacc[d][q]. Epilogue transposes via freed LDS.
__global__ __launch_bounds__(256, 6) void attn_mfma5(
    const u16* __restrict__ Qh, const u16* __restrict__ Ql,
    const u16* __restrict__ Kh, const u16* __restrict__ Kl,
    const u16* __restrict__ Vt,
    const float* __restrict__ qk_gain,
    float* __restrict__ AO) {
  __shared__ __align__(16) u16 SM[12288];   // Kh 8K | Kl 8K | Vt 8K (24KB)
  u16* Kh_s = SM;
  u16* Kl_s = SM + 4096;
  u16* Vt_s = SM + 8192;
  int tid = threadIdx.x;
  int w = tid >> 6, l = tid & 63;
  int qt = 31 - (int)blockIdx.x;
  int q0 = qt * 64;
  int h = blockIdx.y, b = blockIdx.z;
  int kvh = h >> 2;
  const float sc2 = qk_gain[0] * 0.125f * 1.44269504f;   // v_exp_f32 computes 2^x
  // Q B-frags straight from global (col q = w*16 + (l&15))
  short8v qb_h[2], qb_l[2];
  {
    size_t qrow = (size_t)(b * Tc + q0 + w * 16 + (l & 15));
#pragma unroll
    for (int sl = 0; sl < 2; ++sl) {
      int dstart = (l >> 4) * 8 + sl * 32;
      qb_h[sl] = *(const short8v*)&Qh[qrow * Dc + h * 64 + dstart];
      qb_l[sl] = *(const short8v*)&Ql[qrow * Dc + h * 64 + dstart];
    }
  }
  f32x4 Oacc[4] = {{0,0,0,0},{0,0,0,0},{0,0,0,0},{0,0,0,0}};
  float mrow = -3.0e38f, lrow = 0.0f;
  int qmax_w = q0 + w * 16 + 15;
  int qg = q0 + w * 16 + (l & 15);
  int nsteps = qt + 1;
  u16x8 pk[2], pl[2], pv[2];
#define AISSUE3(K0)                                                             \
  {                                                                             \
    _Pragma("unroll") for (int p = 0; p < 2; ++p) {                             \
      int idx = tid + p * 256;                                                  \
      int jj = idx >> 3, cc = idx & 7;                                          \
      size_t kb = ((size_t)(b * Tc + (K0) + jj)) * (HKVc * HDc) + kvh * 64 + cc * 8; \
      pk[p] = *(const u16x8*)&Kh[kb];                                           \
      pl[p] = *(const u16x8*)&Kl[kb];                                           \
      size_t vb = ((size_t)(kvh * 64 + jj)) * (size_t)Mc + b * Tc + (K0) + cc * 8; \
      pv[p] = *(const u16x8*)&Vt[vb];                                           \
    }                                                                           \
  }
  AISSUE3(0)
  for (int stp = 0; stp < nsteps; ++stp) {
    int k0 = stp * 64;
    __syncthreads();
#pragma unroll
    for (int p = 0; p < 2; ++p) {
      int idx = tid + p * 256;
      int jj = idx >> 3, cc = idx & 7;
      int sw = jj * 64 + ((cc * 8) ^ ((jj & 7) << 3));
      *(u16x8*)&Kh_s[sw] = pk[p];
      *(u16x8*)&Kl_s[sw] = pl[p];
      *(u16x8*)&Vt_s[sw] = pv[p];
    }
    if (stp + 1 < nsteps) AISSUE3((stp + 1) * 64)
    __syncthreads();
    if (k0 > qmax_w) continue;   // fully masked for this wave (barriers done)
    // ---- QK^T swapped: s[kt] = K_tile x Q -> S[key][q=l&15] ----
    f32x4 s[4] = {{0,0,0,0},{0,0,0,0},{0,0,0,0},{0,0,0,0}};
    __builtin_amdgcn_s_setprio(1);
#pragma unroll
    for (int kt = 0; kt < 4; ++kt) {
      int key = kt * 16 + (l & 15);
#pragma unroll
      for (int sl = 0; sl < 2; ++sl) {
        int dstart = ((l >> 4) * 8 + 32 * sl) ^ ((key & 7) << 3);
        short8v bh = *(const short8v*)&Kh_s[key * 64 + dstart];
        short8v bl = *(const short8v*)&Kl_s[key * 64 + dstart];
        s[kt] = __builtin_amdgcn_mfma_f32_16x16x32_bf16(bh, qb_h[sl], s[kt], 0, 0, 0);
        s[kt] = __builtin_amdgcn_mfma_f32_16x16x32_bf16(bl, qb_h[sl], s[kt], 0, 0, 0);
        s[kt] = __builtin_amdgcn_mfma_f32_16x16x32_bf16(bh, qb_l[sl], s[kt], 0, 0, 0);
      }
    }
    __builtin_amdgcn_s_setprio(0);
    // ---- causal mask (lane-local; wave-uniform fast path) ----
    bool full = (k0 + 63) <= (q0 + w * 16);
    if (!full) {
#pragma unroll
      for (int kt = 0; kt < 4; ++kt)
#pragma unroll
        for (int r = 0; r < 4; ++r)
          if (k0 + kt * 16 + ((l >> 4) << 2) + r > qg) s[kt][r] = -3.0e38f;
    }
    // ---- softmax: 15 local fmax + 2 shfl ----
    float mk[4];
#pragma unroll
    for (int kt = 0; kt < 4; ++kt)
      mk[kt] = fmaxf(fmaxf(s[kt][0], s[kt][1]), fmaxf(s[kt][2], s[kt][3]));
    float mx = fmaxf(fmaxf(mk[0], mk[1]), fmaxf(mk[2], mk[3]));
    mx = fmaxf(mx, __shfl_xor(mx, 16));
    mx = fmaxf(mx, __shfl_xor(mx, 32));
    float mnew = fmaxf(mrow, mx);
    float msc = mnew * sc2;
    float corr = fast_exp2(__builtin_fmaf(mrow, sc2, -msc));
    mrow = mnew;
    float p[4][4];
    float sk[4];
#pragma unroll
    for (int kt = 0; kt < 4; ++kt) {
#pragma unroll
      for (int r = 0; r < 4; ++r)
        p[kt][r] = fast_exp2(__builtin_fmaf(s[kt][r], sc2, -msc));
      sk[kt] = (p[kt][0] + p[kt][1]) + (p[kt][2] + p[kt][3]);
    }
    float rs = (sk[0] + sk[1]) + (sk[2] + sk[3]);
    rs += __shfl_xor(rs, 16);
    rs += __shfl_xor(rs, 32);
    lrow = lrow * corr + rs;
#pragma unroll
    for (int dt = 0; dt < 4; ++dt) Oacc[dt] *= corr;
    // ---- pack P to bf16 B-frags entirely in-register ----
    short8v fbv[2];
#pragma unroll
    for (int sl = 0; sl < 2; ++sl) {
      union { u32 u[4]; short8v v; } fq;
      fq.u[0] = cvt_pk_bf16(p[2 * sl][0], p[2 * sl][1]);
      fq.u[1] = cvt_pk_bf16(p[2 * sl][2], p[2 * sl][3]);
      fq.u[2] = cvt_pk_bf16(p[2 * sl + 1][0], p[2 * sl + 1][1]);
      fq.u[3] = cvt_pk_bf16(p[2 * sl + 1][2], p[2 * sl + 1][3]);
      fbv[sl] = fq.v;
    }
    // ---- PV swapped: Oacc[d][q] += Vt x P ----
    __builtin_amdgcn_s_setprio(1);
#pragma unroll
    for (int dt = 0; dt < 4; ++dt) {
      int d = dt * 16 + (l & 15);
#pragma unroll
      for (int sl = 0; sl < 2; ++sl) {
        int kstart = ((l >> 4) * 8 + 32 * sl) ^ ((d & 7) << 3);
        short8v fav = *(const short8v*)&Vt_s[d * 64 + kstart];
        Oacc[dt] = __builtin_amdgcn_mfma_f32_16x16x32_bf16(fav, fbv[sl], Oacc[dt], 0, 0, 0);
      }
    }
    __builtin_amdgcn_s_setprio(0);
  }
  // ---- epilogue: transpose Oacc via freed LDS, coalesced AO store ----
  __syncthreads();   // all waves done reading K/V LDS
  float* Es = (float*)SM + w * (16 * 68);
  float invl = 1.0f / lrow;
#pragma unroll
  for (int dt = 0; dt < 4; ++dt)
#pragma unroll
    for (int r = 0; r < 4; ++r)
      Es[(l & 15) * 68 + dt * 16 + ((l >> 4) << 2) + r] = Oacc[dt][r] * invl;
  size_t arow = ((size_t)(b * Tc + q0 + w * 16 + (l >> 2))) * Dc + h * 64 + (l & 3) * 4;
#pragma unroll
  for (int j = 0; j < 4; ++j) {
    float4 vv = *(const float4*)&Es[(l >> 2) * 68 + (l & 3) * 4 + j * 16];
    *(float4*)&AO[arow + j * 16] = vv;
  }
}

// ---------------- launch ----------------
extern "C" void kernel_launch(void* const* d_in, const int* in_sizes, int n_in,
                              void* d_out, int out_size, void* d_ws, size_t ws_size,
                              hipStream_t stream) {
  const float* x    = (const float*)d_in[0];
  const float* q_w  = (const float*)d_in[1];
  const float* q_g  = (const float*)d_in[2];
  const float* k_w  = (const float*)d_in[3];
  const float* k_g  = (const float*)d_in[4];
  const float* v_w  = (const float*)d_in[5];
  const float* o_w  = (const float*)d_in[6];
  const float* o_g  = (const float*)d_in[7];
  const float* qk_g = (const float*)d_in[8];

  // workspace (bytes), peak ~61.2 MB
  char* base = (char*)d_ws;
  u16* Xqh = (u16*)(base + (0ull  << 20));   // 8MB
  u16* Xql = (u16*)(base + (8ull  << 20));   // 8MB
  u16* Xkh = (u16*)(base + (16ull << 20));   // 8MB
  u16* Xkl = (u16*)(base + (24ull << 20));   // 8MB
  u16* Xvh = (u16*)(base + (32ull << 20));   // 8MB
  u16* Xvl = (u16*)(base + (40ull << 20));   // 8MB
  u16* Kh  = (u16*)(base + (48ull << 20));   // 2MB
  u16* Kl  = (u16*)(base + (50ull << 20));   // 2MB
  u16* Vt  = (u16*)(base + (52ull << 20));   // 2MB  [256][4096], slot-permuted per 32
  u16* Wq  = (u16*)(base + (54ull << 20));   // 2MB
  u16* Wk  = (u16*)(base + (56ull << 20));   // 0.5MB
  u16* Wo  = (u16*)(base + (57ull << 20));   // 2MB
  u16* Vwh = (u16*)(base + (59ull << 20));   // 0.5MB
  u16* Vwl = (u16*)(base + (60ull << 20));   // 0.5MB
  float* leaf = (float*)(base + (61ull << 20)); // 18432 floats (Q 8192 | K 2048 | O 8192)
  float* th   = leaf + 18432;                // 3
  // overlays
  float* AO  = (float*)base;                 // 16MB over Xqh/Xql (dead after Q-proj)
  u16* Xoh = Xkh; u16* Xol = Xkl;            // over Xk (dead after K-proj)
  u16* Qh  = Xvh; u16* Ql  = Xvl;            // over Xv (dead after V-proj)

  // 1) numpy-exact fp32 thresholds
  np_leafsum_all<<<576, 256, 0, stream>>>(q_w, k_w, o_w, leaf);
  np_treemean3<<<3, 256, 0, stream>>>(leaf, th);

  // 2) quantize ternary weights -> bf16 + v_w hi/lo split (one launch)
  quant_split_all<<<2560, 256, 0, stream>>>(q_w, k_w, o_w, v_w, th, Wq, Wk, Wo, Vwh, Vwl);

  // 3) RMSNorm(x) -> bf16 hi/lo (q,k gains) + raw-x hi/lo split (V path)
  rmsnorm_split6<<<Mc, 256, 0, stream>>>(x, q_g, k_g, Xqh, Xql, Xkh, Xkl, Xvh, Xvl);

  // 4) projections (MFMA). V first (Q output overlays Xv).
  //    V: Vt[256][4096] = Vw @ x^T (3-pass), slot-permuted columns. 64x64 tiles.
  gemm_mfma<true, 3, 2, 2><<<dim3(64, 4), 256, 0, stream>>>(Vwh, Vwl, Xvh, Xvl, 256, Mc, 1024,
                                                            nullptr, Vt, nullptr);
  //    Q: hi/lo bf16 out, 64x128 tiles -> 512 blocks, 32KB LDS.
  gemm_mfma<false, 1, 2, 4><<<dim3(8, 64), 256, 0, stream>>>(Xqh, Xql, Wq, nullptr, Mc, 1024, 1024,
                                                             nullptr, Qh, Ql);
  //    K: hi/lo bf16 out, 64x64 tiles.
  gemm_mfma<false, 1, 2, 2><<<dim3(4, 64), 256, 0, stream>>>(Xkh, Xkl, Wk, nullptr, Mc, 256, 1024,
                                                             nullptr, Kh, Kl);

  // 5) MFMA causal GQA attention v5 -> AO fp32
  attn_mfma5<<<dim3(32, Hc, Bc), 256, 0, stream>>>(Qh, Ql, Kh, Kl, Vt, qk_g, AO);

  // 6) output bitlinear
  rmsnorm_split6<<<Mc, 256, 0, stream>>>(AO, o_g, nullptr, Xoh, Xol, nullptr, nullptr,
                                         nullptr, nullptr);
  gemm_mfma<false, 0, 2, 4><<<dim3(8, 64), 256, 0, stream>>>(Xoh, Xol, Wo, nullptr, Mc, 1024, 1024,
                                                             (float*)d_out, nullptr, nullptr);
}

// Round 11
// 192.223 us; speedup vs baseline: 1.6012x; 1.6012x over previous
//
#include <hip/hip_runtime.h>
#include <hip/hip_bf16.h>
#include <cstdint>
#include <cstddef>

typedef unsigned short u16;
typedef unsigned int u32;
typedef __attribute__((ext_vector_type(8))) short short8v;   // 8 bf16 MFMA frag
typedef __attribute__((ext_vector_type(4))) float f32x4;     // MFMA accumulator
typedef __attribute__((ext_vector_type(4))) u16 u16x4;
typedef __attribute__((ext_vector_type(8))) u16 u16x8;

// Problem constants
static constexpr int Bc = 2, Tc = 2048, Dc = 1024, Hc = 16, HKVc = 4, HDc = 64;
static constexpr int Mc = Bc * Tc;                 // 4096 rows
static constexpr float EPSc = 1.1920929e-07f;

static __device__ __forceinline__ u16 f2bf(float f) {
  u32 u = __builtin_bit_cast(u32, f);
  return (u16)((u + 0x7fffu + ((u >> 16) & 1u)) >> 16);
}
static __device__ __forceinline__ float bf2f(u16 b) {
  u32 u = ((u32)b) << 16;
  return __builtin_bit_cast(float, u);
}
static __device__ __forceinline__ float fast_exp2(float x) {
  float r;
  asm("v_exp_f32 %0, %1" : "=v"(r) : "v"(x));
  return r;
}
static __device__ __forceinline__ u32 cvt_pk_bf16(float lo, float hi) {
  u32 r;
  asm("v_cvt_pk_bf16_f32 %0, %1, %2" : "=v"(r) : "v"(lo), "v"(hi));
  return r;
}

// ---------------- numpy-exact fp32 pairwise abs-mean (verified round 3/7) ----------------
__global__ __launch_bounds__(256) void np_leafsum_all(const float* __restrict__ q_w,
                                                      const float* __restrict__ k_w,
                                                      const float* __restrict__ o_w,
                                                      float* __restrict__ leaf) {
  int blk = blockIdx.x;
  const float* w;
  float* out;
  int lfbase;
  if (blk < 256)      { w = q_w; out = leaf;         lfbase = blk * 32; }
  else if (blk < 320) { w = k_w; out = leaf + 8192;  lfbase = (blk - 256) * 32; }
  else                { w = o_w; out = leaf + 10240; lfbase = (blk - 320) * 32; }
  int t = threadIdx.x;
  int lf = lfbase + (t >> 3), j = t & 7;
  const float* a = w + (size_t)lf * 128;
  float r = fabsf(a[j]);
#pragma unroll
  for (int i = 8; i < 128; i += 8) r += fabsf(a[i + j]);
  float x = r + __shfl_xor(r, 1);
  float y = x + __shfl_xor(x, 2);
  float z = y + __shfl_xor(y, 4);
  if (j == 0) out[lf] = z;
}

__global__ __launch_bounds__(256) void np_treemean3(const float* __restrict__ leaf,
                                                    float* __restrict__ th) {
  int m = blockIdx.x;
  const float* src = leaf + (m == 0 ? 0 : (m == 1 ? 8192 : 10240));
  int nle = (m == 1) ? 2048 : 8192;
  float inv_n = (m == 1) ? (1.0f / 262144.0f) : (1.0f / 1048576.0f);
  int t = threadIdx.x;
  int chunk = nle >> 8;                      // 32 or 8, power of two
  float v[32];
  for (int i = 0; i < chunk; i += 4) {
    float4 f = *(const float4*)&src[t * chunk + i];
    v[i] = f.x; v[i + 1] = f.y; v[i + 2] = f.z; v[i + 3] = f.w;
  }
  for (int cnt = chunk >> 1; cnt >= 1; cnt >>= 1)
    for (int i = 0; i < cnt; ++i) v[i] = v[2 * i] + v[2 * i + 1];
  float s = v[0];
#pragma unroll
  for (int off = 1; off < 64; off <<= 1) s += __shfl_xor(s, off);
  __shared__ float red[4];
  if ((t & 63) == 0) red[t >> 6] = s;
  __syncthreads();
  if (t == 0) th[m] = ((red[0] + red[1]) + (red[2] + red[3])) * inv_n;
}

// ---------------- fused: ternary quantize (q/k/o) + v_w hi/lo split ----------------
__global__ __launch_bounds__(256) void quant_split_all(const float* __restrict__ q_w,
                                                       const float* __restrict__ k_w,
                                                       const float* __restrict__ o_w,
                                                       const float* __restrict__ v_w,
                                                       const float* __restrict__ th,
                                                       u16* __restrict__ Wq,
                                                       u16* __restrict__ Wk,
                                                       u16* __restrict__ Wo,
                                                       u16* __restrict__ Vwh,
                                                       u16* __restrict__ Vwl) {
  int i4 = blockIdx.x * 256 + threadIdx.x;   // float4 index
  if (i4 < 589824) {
    const float* w; u16* o; float t;
    int j;
    if (i4 < 262144)      { w = q_w; o = Wq; t = th[0]; j = i4; }
    else if (i4 < 327680) { w = k_w; o = Wk; t = th[1]; j = i4 - 262144; }
    else                  { w = o_w; o = Wo; t = th[2]; j = i4 - 327680; }
    float4 v = *(const float4*)&w[(size_t)j * 4];
    float y[4] = {v.x, v.y, v.z, v.w};
    u16x4 q;
#pragma unroll
    for (int c = 0; c < 4; ++c)
      q[c] = (y[c] > t) ? (u16)0x3F80 : ((y[c] < -t) ? (u16)0xBF80 : (u16)0);
    *(u16x4*)&o[(size_t)j * 4] = q;
  } else {
    int j = i4 - 589824;                     // v_w float4 index, [0, 65536)
    float4 v = *(const float4*)&v_w[(size_t)j * 4];
    float y[4] = {v.x, v.y, v.z, v.w};
    u16x4 h, l;
#pragma unroll
    for (int c = 0; c < 4; ++c) {
      u16 hb = f2bf(y[c]);
      h[c] = hb;
      l[c] = f2bf(y[c] - bf2f(hb));
    }
    *(u16x4*)&Vwh[(size_t)j * 4] = h;
    *(u16x4*)&Vwl[(size_t)j * 4] = l;
  }
}

// ---------------- RMSNorm -> bf16 hi/lo (2 gains) + raw-x hi/lo split ----------------
__global__ __launch_bounds__(256) void rmsnorm_split6(const float* __restrict__ X,
                                                      const float* __restrict__ g1,
                                                      const float* __restrict__ g2,
                                                      u16* __restrict__ H1, u16* __restrict__ L1,
                                                      u16* __restrict__ H2, u16* __restrict__ L2,
                                                      u16* __restrict__ HV, u16* __restrict__ LV) {
  int row = blockIdx.x;
  const float* xr = X + (size_t)row * Dc;
  int tid = threadIdx.x;
  float4 v = *(const float4*)&xr[tid * 4];
  float vv[4] = {v.x, v.y, v.z, v.w};
  if (HV != nullptr) {           // raw x split for the V path
    u16x4 h, l;
#pragma unroll
    for (int j = 0; j < 4; ++j) {
      u16 hb = f2bf(vv[j]);
      h[j] = hb;
      l[j] = f2bf(vv[j] - bf2f(hb));
    }
    *(u16x4*)&HV[(size_t)row * Dc + tid * 4] = h;
    *(u16x4*)&LV[(size_t)row * Dc + tid * 4] = l;
  }
  float ss = v.x * v.x + v.y * v.y + v.z * v.z + v.w * v.w;
#pragma unroll
  for (int off = 1; off < 64; off <<= 1) ss += __shfl_xor(ss, off);
  __shared__ float red[4];
  if ((tid & 63) == 0) red[tid >> 6] = ss;
  __syncthreads();
  float tot = red[0] + red[1] + red[2] + red[3];
  float inv = 1.0f / sqrtf(tot * (1.0f / (float)Dc) + EPSc);
  {
    float4 a = *(const float4*)&g1[tid * 4];
    float ga[4] = {a.x, a.y, a.z, a.w};
    u16x4 h, l;
#pragma unroll
    for (int j = 0; j < 4; ++j) {
      float y = vv[j] * inv * ga[j];
      u16 hb = f2bf(y);
      h[j] = hb;
      l[j] = f2bf(y - bf2f(hb));
    }
    *(u16x4*)&H1[(size_t)row * Dc + tid * 4] = h;
    *(u16x4*)&L1[(size_t)row * Dc + tid * 4] = l;
  }
  if (g2 != nullptr) {
    float4 a = *(const float4*)&g2[tid * 4];
    float ga[4] = {a.x, a.y, a.z, a.w};
    u16x4 h, l;
#pragma unroll
    for (int j = 0; j < 4; ++j) {
      float y = vv[j] * inv * ga[j];
      u16 hb = f2bf(y);
      h[j] = hb;
      l[j] = f2bf(y - bf2f(hb));
    }
    *(u16x4*)&H2[(size_t)row * Dc + tid * 4] = h;
    *(u16x4*)&L2[(size_t)row * Dc + tid * 4] = l;
  }
}

// ---------------- bf16 MFMA GEMM, templated tile ----------------
// MODE 0: C fp32.  MODE 1: O1/O2 = bf16 hi/lo.  MODE 3: O1 = bf16, cols permuted
// within each 32-block by gp(k) = (k&~31) | ((k>>2)&3)<<3 | ((k>>4)&1)<<2 | (k&3)
// (matches attn's in-register P slot order for the swapped-PV MFMA; verified r9/r10).
template <bool PB, int MODE, int MF, int NF>
__global__ __launch_bounds__(256, 1) void gemm_mfma(
    const u16* __restrict__ Ah, const u16* __restrict__ Al,
    const u16* __restrict__ Bh, const u16* __restrict__ Bl,
    int M, int N, int K,
    float* __restrict__ C, u16* __restrict__ O1, u16* __restrict__ O2) {
  constexpr int BM = MF * 32, BN = NF * 32;
  constexpr int APT = BM / 32;               // u16x8 loads per thread for A tile
  constexpr int BPT = BN / 32;
  __shared__ __align__(16) u16 AhS[BM * 64], AlS[BM * 64];
  __shared__ __align__(16) u16 BhS[BN * 64];
  __shared__ __align__(16) u16 BlS[PB ? BN * 64 : 8];
  int tid = threadIdx.x;
  int l = tid & 63, w = tid >> 6;
  int wm = (w >> 1) * (BM / 2), wn = (w & 1) * (BN / 2);
  int bm = blockIdx.y * BM, bn = blockIdx.x * BN;
  u16x8 rAh[APT], rAl[APT], rBh[BPT], rBl[PB ? BPT : 1];
  f32x4 acc[MF][NF] = {};
#define LOADTILE(kb_)                                                               \
  {                                                                                 \
    _Pragma("unroll") for (int p = 0; p < APT; ++p) {                               \
      int idx = tid + p * 256;                                                      \
      int row = idx >> 3, cc = idx & 7;                                             \
      rAh[p] = *(const u16x8*)&Ah[(size_t)(bm + row) * K + (kb_) + cc * 8];         \
      rAl[p] = *(const u16x8*)&Al[(size_t)(bm + row) * K + (kb_) + cc * 8];         \
    }                                                                               \
    _Pragma("unroll") for (int p = 0; p < BPT; ++p) {                               \
      int idx = tid + p * 256;                                                      \
      int row = idx >> 3, cc = idx & 7;                                             \
      rBh[p] = *(const u16x8*)&Bh[(size_t)(bn + row) * K + (kb_) + cc * 8];         \
      if (PB) rBl[p] = *(const u16x8*)&Bl[(size_t)(bn + row) * K + (kb_) + cc * 8]; \
    }                                                                               \
  }
  LOADTILE(0)
  for (int kb = 0; kb < K; kb += 64) {
    __syncthreads();
#pragma unroll
    for (int p = 0; p < APT; ++p) {
      int idx = tid + p * 256;
      int row = idx >> 3, cc = idx & 7;
      int off = row * 64 + ((cc * 8) ^ ((row & 7) << 3));
      *(u16x8*)&AhS[off] = rAh[p];
      *(u16x8*)&AlS[off] = rAl[p];
    }
#pragma unroll
    for (int p = 0; p < BPT; ++p) {
      int idx = tid + p * 256;
      int row = idx >> 3, cc = idx & 7;
      int off = row * 64 + ((cc * 8) ^ ((row & 7) << 3));
      *(u16x8*)&BhS[off] = rBh[p];
      if (PB) *(u16x8*)&BlS[off] = rBl[p];
    }
    if (kb + 64 < K) LOADTILE(kb + 64)
    __syncthreads();
    __builtin_amdgcn_s_setprio(1);
#pragma unroll
    for (int sl = 0; sl < 2; ++sl) {
      short8v fa[MF], fal[MF], fb[NF], fbl[NF];
      int kof = (l >> 4) * 8 + sl * 32;
#pragma unroll
      for (int m = 0; m < MF; ++m) {
        int row = wm + m * 16 + (l & 15);
        int off = row * 64 + (kof ^ ((row & 7) << 3));
        fa[m] = *(const short8v*)&AhS[off];
        fal[m] = *(const short8v*)&AlS[off];
      }
#pragma unroll
      for (int n = 0; n < NF; ++n) {
        int row = wn + n * 16 + (l & 15);
        int off = row * 64 + (kof ^ ((row & 7) << 3));
        fb[n] = *(const short8v*)&BhS[off];
        if (PB) fbl[n] = *(const short8v*)&BlS[off];
      }
#pragma unroll
      for (int m = 0; m < MF; ++m)
#pragma unroll
        for (int n = 0; n < NF; ++n) {
          acc[m][n] = __builtin_amdgcn_mfma_f32_16x16x32_bf16(fa[m], fb[n], acc[m][n], 0, 0, 0);
          acc[m][n] = __builtin_amdgcn_mfma_f32_16x16x32_bf16(fal[m], fb[n], acc[m][n], 0, 0, 0);
          if (PB)
            acc[m][n] = __builtin_amdgcn_mfma_f32_16x16x32_bf16(fa[m], fbl[n], acc[m][n], 0, 0, 0);
        }
    }
    __builtin_amdgcn_s_setprio(0);
  }
#undef LOADTILE
#pragma unroll
  for (int m = 0; m < MF; ++m)
#pragma unroll
    for (int n = 0; n < NF; ++n)
#pragma unroll
      for (int r = 0; r < 4; ++r) {
        int grow = bm + wm + m * 16 + (l >> 4) * 4 + r;
        int gcol = bn + wn + n * 16 + (l & 15);
        float v = acc[m][n][r];
        if (MODE == 0) {
          C[(size_t)grow * N + gcol] = v;
        } else if (MODE == 1) {
          u16 hb = f2bf(v);
          O1[(size_t)grow * N + gcol] = hb;
          O2[(size_t)grow * N + gcol] = f2bf(v - bf2f(hb));
        } else {
          int k = gcol & 31;
          int gp = (gcol & ~31) | (((k >> 2) & 3) << 3) |
                   (((k >> 4) & 1) << 2) | (k & 3);
          O1[(size_t)grow * N + gp] = f2bf(v);
        }
      }
}

// ---------------- MFMA causal GQA attention v6 (swapped + pair-balanced) ----------------
// TK=128, grid (16, H, B): block processes q-tiles (31-pr) then pr -> uniform ~17.5 steps.
// 48KB LDS -> 3 blocks/CU capacity; 512 blocks = full residency. launch_bounds(256,3): VGPR cap 168.
// s = mfma(K, Q): lane holds S[key][q=l&15]; softmax lane-local + 2 shfl.
// PV = mfma(Vt, P-in-register): no Ps LDS. Oacc[d][q]; epilogue transposes via freed LDS.
__global__ __launch_bounds__(256, 3) void attn_mfma6(
    const u16* __restrict__ Qh, const u16* __restrict__ Ql,
    const u16* __restrict__ Kh, const u16* __restrict__ Kl,
    const u16* __restrict__ Vt,
    const float* __restrict__ qk_gain,
    float* __restrict__ AO) {
  __shared__ __align__(16) u16 SM[24576];   // Kh 16KB | Kl 16KB | Vt 16KB
  u16* Kh_s = SM;
  u16* Kl_s = SM + 8192;
  u16* Vt_s = SM + 16384;
  int tid = threadIdx.x;
  int w = tid >> 6, l = tid & 63;
  int pr = blockIdx.x;                 // 0..15
  int h = blockIdx.y, b = blockIdx.z;
  int kvh = h >> 2;
  const float sc2 = qk_gain[0] * 0.125f * 1.44269504f;   // v_exp_f32 computes 2^x
  u16x8 pk[4], pl[4], pv[4];
#define AISSUE2(K0)                                                             \
  {                                                                             \
    _Pragma("unroll") for (int p = 0; p < 4; ++p) {                             \
      int idx = tid + p * 256;                                                  \
      int jj = idx >> 3, cc = idx & 7;                                          \
      size_t kb = ((size_t)(b * Tc + (K0) + jj)) * (HKVc * HDc) + kvh * 64 + cc * 8; \
      pk[p] = *(const u16x8*)&Kh[kb];                                           \
      pl[p] = *(const u16x8*)&Kl[kb];                                           \
      int d = idx >> 4, c16 = idx & 15;                                         \
      size_t vb = ((size_t)(kvh * 64 + d)) * (size_t)Mc + b * Tc + (K0) + c16 * 8; \
      pv[p] = *(const u16x8*)&Vt[vb];                                           \
    }                                                                           \
  }
  for (int pass = 0; pass < 2; ++pass) {
    int qt = pass == 0 ? (31 - pr) : pr;
    int q0 = qt * 64;
    // Q B-frags straight from global (col q = w*16 + (l&15))
    short8v qb_h[2], qb_l[2];
    {
      size_t qrow = (size_t)(b * Tc + q0 + w * 16 + (l & 15));
#pragma unroll
      for (int sl = 0; sl < 2; ++sl) {
        int dstart = (l >> 4) * 8 + sl * 32;
        qb_h[sl] = *(const short8v*)&Qh[qrow * Dc + h * 64 + dstart];
        qb_l[sl] = *(const short8v*)&Ql[qrow * Dc + h * 64 + dstart];
      }
    }
    f32x4 Oacc[4] = {{0,0,0,0},{0,0,0,0},{0,0,0,0},{0,0,0,0}};
    float mrow = -3.0e38f, lrow = 0.0f;
    int qmax_w = q0 + w * 16 + 15;
    int qg = q0 + w * 16 + (l & 15);
    int nsteps = qt / 2 + 1;
    AISSUE2(0)
    for (int stp = 0; stp < nsteps; ++stp) {
      int k0 = stp * 128;
      __syncthreads();   // staging buffers free (prev compute + prev epilogue done)
#pragma unroll
      for (int p = 0; p < 4; ++p) {
        int idx = tid + p * 256;
        int jj = idx >> 3, cc = idx & 7;
        *(u16x8*)&Kh_s[jj * 64 + ((cc * 8) ^ ((jj & 7) << 3))] = pk[p];
        *(u16x8*)&Kl_s[jj * 64 + ((cc * 8) ^ ((jj & 7) << 3))] = pl[p];
        int d = idx >> 4, c16 = idx & 15;
        *(u16x8*)&Vt_s[d * 128 + ((c16 * 8) ^ ((d & 7) << 3))] = pv[p];
      }
      if (stp + 1 < nsteps) AISSUE2((stp + 1) * 128)
      __syncthreads();
      if (k0 > qmax_w) continue;   // fully masked for this wave (barriers done)
      // ---- QK^T swapped: s[kt] = K_tile x Q -> S[key][q=l&15] ----
      f32x4 s[8] = {{0,0,0,0},{0,0,0,0},{0,0,0,0},{0,0,0,0},
                    {0,0,0,0},{0,0,0,0},{0,0,0,0},{0,0,0,0}};
      __builtin_amdgcn_s_setprio(1);
#pragma unroll
      for (int kt = 0; kt < 8; ++kt) {
        int key = kt * 16 + (l & 15);
#pragma unroll
        for (int sl = 0; sl < 2; ++sl) {
          int dstart = ((l >> 4) * 8 + 32 * sl) ^ ((key & 7) << 3);
          short8v bh = *(const short8v*)&Kh_s[key * 64 + dstart];
          short8v bl = *(const short8v*)&Kl_s[key * 64 + dstart];
          s[kt] = __builtin_amdgcn_mfma_f32_16x16x32_bf16(bh, qb_h[sl], s[kt], 0, 0, 0);
          s[kt] = __builtin_amdgcn_mfma_f32_16x16x32_bf16(bl, qb_h[sl], s[kt], 0, 0, 0);
          s[kt] = __builtin_amdgcn_mfma_f32_16x16x32_bf16(bh, qb_l[sl], s[kt], 0, 0, 0);
        }
      }
      __builtin_amdgcn_s_setprio(0);
      // ---- causal mask (lane-local; wave-uniform fast path) ----
      bool full = (k0 + 127) <= (q0 + w * 16);
      if (!full) {
#pragma unroll
        for (int kt = 0; kt < 8; ++kt)
#pragma unroll
          for (int r = 0; r < 4; ++r)
            if (k0 + kt * 16 + ((l >> 4) << 2) + r > qg) s[kt][r] = -3.0e38f;
      }
      // ---- softmax: 31 local fmax + 2 shfl ----
      float mk[8];
#pragma unroll
      for (int kt = 0; kt < 8; ++kt)
        mk[kt] = fmaxf(fmaxf(s[kt][0], s[kt][1]), fmaxf(s[kt][2], s[kt][3]));
      float mx = fmaxf(fmaxf(fmaxf(mk[0], mk[1]), fmaxf(mk[2], mk[3])),
                       fmaxf(fmaxf(mk[4], mk[5]), fmaxf(mk[6], mk[7])));
      mx = fmaxf(mx, __shfl_xor(mx, 16));
      mx = fmaxf(mx, __shfl_xor(mx, 32));
      float mnew = fmaxf(mrow, mx);
      float msc = mnew * sc2;
      float corr = fast_exp2(__builtin_fmaf(mrow, sc2, -msc));
      mrow = mnew;
      float p[8][4];
      float sk[8];
#pragma unroll
      for (int kt = 0; kt < 8; ++kt) {
#pragma unroll
        for (int r = 0; r < 4; ++r)
          p[kt][r] = fast_exp2(__builtin_fmaf(s[kt][r], sc2, -msc));
        sk[kt] = (p[kt][0] + p[kt][1]) + (p[kt][2] + p[kt][3]);
      }
      float rs = ((sk[0] + sk[1]) + (sk[2] + sk[3])) + ((sk[4] + sk[5]) + (sk[6] + sk[7]));
      rs += __shfl_xor(rs, 16);
      rs += __shfl_xor(rs, 32);
      lrow = lrow * corr + rs;
#pragma unroll
      for (int dt = 0; dt < 4; ++dt) Oacc[dt] *= corr;
      // ---- pack P to bf16 B-frags entirely in-register (slot order = MODE 3 perm) ----
      short8v fbv[4];
#pragma unroll
      for (int sl = 0; sl < 4; ++sl) {
        union { u32 u[4]; short8v v; } fq;
        fq.u[0] = cvt_pk_bf16(p[2 * sl][0], p[2 * sl][1]);
        fq.u[1] = cvt_pk_bf16(p[2 * sl][2], p[2 * sl][3]);
        fq.u[2] = cvt_pk_bf16(p[2 * sl + 1][0], p[2 * sl + 1][1]);
        fq.u[3] = cvt_pk_bf16(p[2 * sl + 1][2], p[2 * sl + 1][3]);
        fbv[sl] = fq.v;
      }
      // ---- PV swapped: Oacc[d][q] += Vt x P ----
      __builtin_amdgcn_s_setprio(1);
#pragma unroll
      for (int dt = 0; dt < 4; ++dt) {
        int d = dt * 16 + (l & 15);
#pragma unroll
        for (int sl = 0; sl < 4; ++sl) {
          int kstart = ((l >> 4) * 8 + 32 * sl) ^ ((d & 7) << 3);
          short8v fav = *(const short8v*)&Vt_s[d * 128 + kstart];
          Oacc[dt] = __builtin_amdgcn_mfma_f32_16x16x32_bf16(fav, fbv[sl], Oacc[dt], 0, 0, 0);
        }
      }
      __builtin_amdgcn_s_setprio(0);
    }
    // ---- epilogue: transpose Oacc via freed LDS, coalesced AO store ----
    __syncthreads();   // all waves done reading K/V LDS this pass
    float* Es = (float*)SM + w * (16 * 68);
    float invl = 1.0f / lrow;
#pragma unroll
    for (int dt = 0; dt < 4; ++dt)
#pragma unroll
      for (int r = 0; r < 4; ++r)
        Es[(l & 15) * 68 + dt * 16 + ((l >> 4) << 2) + r] = Oacc[dt][r] * invl;
    size_t arow = ((size_t)(b * Tc + q0 + w * 16 + (l >> 2))) * Dc + h * 64 + (l & 3) * 4;
#pragma unroll
    for (int j = 0; j < 4; ++j) {
      float4 vv = *(const float4*)&Es[(l >> 2) * 68 + (l & 3) * 4 + j * 16];
      *(float4*)&AO[arow + j * 16] = vv;
    }
    // next pass's loop-top __syncthreads() protects Es before staging overwrites it
  }
}

// ---------------- launch ----------------
extern "C" void kernel_launch(void* const* d_in, const int* in_sizes, int n_in,
                              void* d_out, int out_size, void* d_ws, size_t ws_size,
                              hipStream_t stream) {
  const float* x    = (const float*)d_in[0];
  const float* q_w  = (const float*)d_in[1];
  const float* q_g  = (const float*)d_in[2];
  const float* k_w  = (const float*)d_in[3];
  const float* k_g  = (const float*)d_in[4];
  const float* v_w  = (const float*)d_in[5];
  const float* o_w  = (const float*)d_in[6];
  const float* o_g  = (const float*)d_in[7];
  const float* qk_g = (const float*)d_in[8];

  // workspace (bytes), peak ~61.2 MB
  char* base = (char*)d_ws;
  u16* Xqh = (u16*)(base + (0ull  << 20));   // 8MB
  u16* Xql = (u16*)(base + (8ull  << 20));   // 8MB
  u16* Xkh = (u16*)(base + (16ull << 20));   // 8MB
  u16* Xkl = (u16*)(base + (24ull << 20));   // 8MB
  u16* Xvh = (u16*)(base + (32ull << 20));   // 8MB
  u16* Xvl = (u16*)(base + (40ull << 20));   // 8MB
  u16* Kh  = (u16*)(base + (48ull << 20));   // 2MB
  u16* Kl  = (u16*)(base + (50ull << 20));   // 2MB
  u16* Vt  = (u16*)(base + (52ull << 20));   // 2MB  [256][4096], slot-permuted per 32
  u16* Wq  = (u16*)(base + (54ull << 20));   // 2MB
  u16* Wk  = (u16*)(base + (56ull << 20));   // 0.5MB
  u16* Wo  = (u16*)(base + (57ull << 20));   // 2MB
  u16* Vwh = (u16*)(base + (59ull << 20));   // 0.5MB
  u16* Vwl = (u16*)(base + (60ull << 20));   // 0.5MB
  float* leaf = (float*)(base + (61ull << 20)); // 18432 floats (Q 8192 | K 2048 | O 8192)
  float* th   = leaf + 18432;                // 3
  // overlays
  float* AO  = (float*)base;                 // 16MB over Xqh/Xql (dead after Q-proj)
  u16* Xoh = Xkh; u16* Xol = Xkl;            // over Xk (dead after K-proj)
  u16* Qh  = Xvh; u16* Ql  = Xvl;            // over Xv (dead after V-proj)

  // 1) numpy-exact fp32 thresholds
  np_leafsum_all<<<576, 256, 0, stream>>>(q_w, k_w, o_w, leaf);
  np_treemean3<<<3, 256, 0, stream>>>(leaf, th);

  // 2) quantize ternary weights -> bf16 + v_w hi/lo split (one launch)
  quant_split_all<<<2560, 256, 0, stream>>>(q_w, k_w, o_w, v_w, th, Wq, Wk, Wo, Vwh, Vwl);

  // 3) RMSNorm(x) -> bf16 hi/lo (q,k gains) + raw-x hi/lo split (V path)
  rmsnorm_split6<<<Mc, 256, 0, stream>>>(x, q_g, k_g, Xqh, Xql, Xkh, Xkl, Xvh, Xvl);

  // 4) projections (MFMA). V first (Q output overlays Xv).
  //    V: Vt[256][4096] = Vw @ x^T (3-pass), slot-permuted columns. 64x64 tiles.
  gemm_mfma<true, 3, 2, 2><<<dim3(64, 4), 256, 0, stream>>>(Vwh, Vwl, Xvh, Xvl, 256, Mc, 1024,
                                                            nullptr, Vt, nullptr);
  //    Q: hi/lo bf16 out, 64x128 tiles -> 512 blocks, 32KB LDS.
  gemm_mfma<false, 1, 2, 4><<<dim3(8, 64), 256, 0, stream>>>(Xqh, Xql, Wq, nullptr, Mc, 1024, 1024,
                                                             nullptr, Qh, Ql);
  //    K: hi/lo bf16 out, 64x64 tiles.
  gemm_mfma<false, 1, 2, 2><<<dim3(4, 64), 256, 0, stream>>>(Xkh, Xkl, Wk, nullptr, Mc, 256, 1024,
                                                             nullptr, Kh, Kl);

  // 5) MFMA causal GQA attention v6 -> AO fp32
  attn_mfma6<<<dim3(16, Hc, Bc), 256, 0, stream>>>(Qh, Ql, Kh, Kl, Vt, qk_g, AO);

  // 6) output bitlinear
  rmsnorm_split6<<<Mc, 256, 0, stream>>>(AO, o_g, nullptr, Xoh, Xol, nullptr, nullptr,
                                         nullptr, nullptr);
  gemm_mfma<false, 0, 2, 4><<<dim3(8, 64), 256, 0, stream>>>(Xoh, Xol, Wo, nullptr, Mc, 1024, 1024,
                                                             (float*)d_out, nullptr, nullptr);
}

// Round 12
// 165.993 us; speedup vs baseline: 1.8542x; 1.1580x over previous
//
#include <hip/hip_runtime.h>
#include <hip/hip_bf16.h>
#include <cstdint>
#include <cstddef>

typedef unsigned short u16;
typedef unsigned int u32;
typedef __attribute__((ext_vector_type(8))) short short8v;   // 8 bf16 MFMA frag
typedef __attribute__((ext_vector_type(4))) float f32x4;     // MFMA accumulator
typedef __attribute__((ext_vector_type(4))) u16 u16x4;
typedef __attribute__((ext_vector_type(8))) u16 u16x8;

// Problem constants
static constexpr int Bc = 2, Tc = 2048, Dc = 1024, Hc = 16, HKVc = 4, HDc = 64;
static constexpr int Mc = Bc * Tc;                 // 4096 rows
static constexpr float EPSc = 1.1920929e-07f;

static __device__ __forceinline__ u16 f2bf(float f) {
  u32 u = __builtin_bit_cast(u32, f);
  return (u16)((u + 0x7fffu + ((u >> 16) & 1u)) >> 16);
}
static __device__ __forceinline__ float bf2f(u16 b) {
  u32 u = ((u32)b) << 16;
  return __builtin_bit_cast(float, u);
}
static __device__ __forceinline__ float fast_exp2(float x) {
  float r;
  asm("v_exp_f32 %0, %1" : "=v"(r) : "v"(x));
  return r;
}
static __device__ __forceinline__ u32 cvt_pk_bf16(float lo, float hi) {
  u32 r;
  asm("v_cvt_pk_bf16_f32 %0, %1, %2" : "=v"(r) : "v"(lo), "v"(hi));
  return r;
}

// ---------------- numpy-exact fp32 pairwise abs-mean (verified round 3/7) ----------------
__global__ __launch_bounds__(256) void np_leafsum_all(const float* __restrict__ q_w,
                                                      const float* __restrict__ k_w,
                                                      const float* __restrict__ o_w,
                                                      float* __restrict__ leaf) {
  int blk = blockIdx.x;
  const float* w;
  float* out;
  int lfbase;
  if (blk < 256)      { w = q_w; out = leaf;         lfbase = blk * 32; }
  else if (blk < 320) { w = k_w; out = leaf + 8192;  lfbase = (blk - 256) * 32; }
  else                { w = o_w; out = leaf + 10240; lfbase = (blk - 320) * 32; }
  int t = threadIdx.x;
  int lf = lfbase + (t >> 3), j = t & 7;
  const float* a = w + (size_t)lf * 128;
  float r = fabsf(a[j]);
#pragma unroll
  for (int i = 8; i < 128; i += 8) r += fabsf(a[i + j]);
  float x = r + __shfl_xor(r, 1);
  float y = x + __shfl_xor(x, 2);
  float z = y + __shfl_xor(y, 4);
  if (j == 0) out[lf] = z;
}

__global__ __launch_bounds__(256) void np_treemean3(const float* __restrict__ leaf,
                                                    float* __restrict__ th) {
  int m = blockIdx.x;
  const float* src = leaf + (m == 0 ? 0 : (m == 1 ? 8192 : 10240));
  int nle = (m == 1) ? 2048 : 8192;
  float inv_n = (m == 1) ? (1.0f / 262144.0f) : (1.0f / 1048576.0f);
  int t = threadIdx.x;
  int chunk = nle >> 8;                      // 32 or 8, power of two
  float v[32];
  for (int i = 0; i < chunk; i += 4) {
    float4 f = *(const float4*)&src[t * chunk + i];
    v[i] = f.x; v[i + 1] = f.y; v[i + 2] = f.z; v[i + 3] = f.w;
  }
  for (int cnt = chunk >> 1; cnt >= 1; cnt >>= 1)
    for (int i = 0; i < cnt; ++i) v[i] = v[2 * i] + v[2 * i + 1];
  float s = v[0];
#pragma unroll
  for (int off = 1; off < 64; off <<= 1) s += __shfl_xor(s, off);
  __shared__ float red[4];
  if ((t & 63) == 0) red[t >> 6] = s;
  __syncthreads();
  if (t == 0) th[m] = ((red[0] + red[1]) + (red[2] + red[3])) * inv_n;
}

// ---------------- fused: ternary quantize (q/k/o) + v_w bf16 cast ----------------
__global__ __launch_bounds__(256) void quant_split_all(const float* __restrict__ q_w,
                                                       const float* __restrict__ k_w,
                                                       const float* __restrict__ o_w,
                                                       const float* __restrict__ v_w,
                                                       const float* __restrict__ th,
                                                       u16* __restrict__ Wq,
                                                       u16* __restrict__ Wk,
                                                       u16* __restrict__ Wo,
                                                       u16* __restrict__ Vwh) {
  int i4 = blockIdx.x * 256 + threadIdx.x;   // float4 index
  if (i4 < 589824) {
    const float* w; u16* o; float t;
    int j;
    if (i4 < 262144)      { w = q_w; o = Wq; t = th[0]; j = i4; }
    else if (i4 < 327680) { w = k_w; o = Wk; t = th[1]; j = i4 - 262144; }
    else                  { w = o_w; o = Wo; t = th[2]; j = i4 - 327680; }
    float4 v = *(const float4*)&w[(size_t)j * 4];
    float y[4] = {v.x, v.y, v.z, v.w};
    u16x4 q;
#pragma unroll
    for (int c = 0; c < 4; ++c)
      q[c] = (y[c] > t) ? (u16)0x3F80 : ((y[c] < -t) ? (u16)0xBF80 : (u16)0);
    *(u16x4*)&o[(size_t)j * 4] = q;
  } else {
    int j = i4 - 589824;                     // v_w float4 index, [0, 65536)
    float4 v = *(const float4*)&v_w[(size_t)j * 4];
    float y[4] = {v.x, v.y, v.z, v.w};
    u16x4 h;
#pragma unroll
    for (int c = 0; c < 4; ++c) h[c] = f2bf(y[c]);
    *(u16x4*)&Vwh[(size_t)j * 4] = h;
  }
}

// ---------------- RMSNorm -> bf16 (hi or hi/lo) x2 gains + raw-x bf16 ----------------
__global__ __launch_bounds__(256) void rmsnorm_split6(const float* __restrict__ X,
                                                      const float* __restrict__ g1,
                                                      const float* __restrict__ g2,
                                                      u16* __restrict__ H1, u16* __restrict__ L1,
                                                      u16* __restrict__ H2, u16* __restrict__ L2,
                                                      u16* __restrict__ HV) {
  int row = blockIdx.x;
  const float* xr = X + (size_t)row * Dc;
  int tid = threadIdx.x;
  float4 v = *(const float4*)&xr[tid * 4];
  float vv[4] = {v.x, v.y, v.z, v.w};
  if (HV != nullptr) {           // raw x bf16 for the single-pass V path
    u16x4 h;
#pragma unroll
    for (int j = 0; j < 4; ++j) h[j] = f2bf(vv[j]);
    *(u16x4*)&HV[(size_t)row * Dc + tid * 4] = h;
  }
  float ss = v.x * v.x + v.y * v.y + v.z * v.z + v.w * v.w;
#pragma unroll
  for (int off = 1; off < 64; off <<= 1) ss += __shfl_xor(ss, off);
  __shared__ float red[4];
  if ((tid & 63) == 0) red[tid >> 6] = ss;
  __syncthreads();
  float tot = red[0] + red[1] + red[2] + red[3];
  float inv = 1.0f / sqrtf(tot * (1.0f / (float)Dc) + EPSc);
  {
    float4 a = *(const float4*)&g1[tid * 4];
    float ga[4] = {a.x, a.y, a.z, a.w};
    u16x4 h, l;
#pragma unroll
    for (int j = 0; j < 4; ++j) {
      float y = vv[j] * inv * ga[j];
      u16 hb = f2bf(y);
      h[j] = hb;
      l[j] = f2bf(y - bf2f(hb));
    }
    *(u16x4*)&H1[(size_t)row * Dc + tid * 4] = h;
    if (L1 != nullptr) *(u16x4*)&L1[(size_t)row * Dc + tid * 4] = l;
  }
  if (g2 != nullptr) {
    float4 a = *(const float4*)&g2[tid * 4];
    float ga[4] = {a.x, a.y, a.z, a.w};
    u16x4 h, l;
#pragma unroll
    for (int j = 0; j < 4; ++j) {
      float y = vv[j] * inv * ga[j];
      u16 hb = f2bf(y);
      h[j] = hb;
      l[j] = f2bf(y - bf2f(hb));
    }
    *(u16x4*)&H2[(size_t)row * Dc + tid * 4] = h;
    if (L2 != nullptr) *(u16x4*)&L2[(size_t)row * Dc + tid * 4] = l;
  }
}

// ---------------- bf16 MFMA GEMM, templated tile + optional A-lo / B-lo passes ----------------
// MODE 0: C fp32.  MODE 1: O1/O2 = bf16 hi/lo.  MODE 3: O1 = bf16, cols permuted
// within each 32-block by gp(k) = (k&~31) | ((k>>2)&3)<<3 | ((k>>4)&1)<<2 | (k&3)
// (matches attn's in-register P slot order for the swapped-PV MFMA; verified r9-r11).
template <bool PA, bool PB, int MODE, int MF, int NF>
__global__ __launch_bounds__(256, 1) void gemm_mfma(
    const u16* __restrict__ Ah, const u16* __restrict__ Al,
    const u16* __restrict__ Bh, const u16* __restrict__ Bl,
    int M, int N, int K,
    float* __restrict__ C, u16* __restrict__ O1, u16* __restrict__ O2) {
  constexpr int BM = MF * 32, BN = NF * 32;
  constexpr int APT = BM / 32;               // u16x8 loads per thread for A tile
  constexpr int BPT = BN / 32;
  __shared__ __align__(16) u16 AhS[BM * 64];
  __shared__ __align__(16) u16 AlS[PA ? BM * 64 : 8];
  __shared__ __align__(16) u16 BhS[BN * 64];
  __shared__ __align__(16) u16 BlS[PB ? BN * 64 : 8];
  int tid = threadIdx.x;
  int l = tid & 63, w = tid >> 6;
  int wm = (w >> 1) * (BM / 2), wn = (w & 1) * (BN / 2);
  int bm = blockIdx.y * BM, bn = blockIdx.x * BN;
  u16x8 rAh[APT], rAl[PA ? APT : 1], rBh[BPT], rBl[PB ? BPT : 1];
  f32x4 acc[MF][NF] = {};
#define LOADTILE(kb_)                                                               \
  {                                                                                 \
    _Pragma("unroll") for (int p = 0; p < APT; ++p) {                               \
      int idx = tid + p * 256;                                                      \
      int row = idx >> 3, cc = idx & 7;                                             \
      rAh[p] = *(const u16x8*)&Ah[(size_t)(bm + row) * K + (kb_) + cc * 8];         \
      if (PA) rAl[p] = *(const u16x8*)&Al[(size_t)(bm + row) * K + (kb_) + cc * 8]; \
    }                                                                               \
    _Pragma("unroll") for (int p = 0; p < BPT; ++p) {                               \
      int idx = tid + p * 256;                                                      \
      int row = idx >> 3, cc = idx & 7;                                             \
      rBh[p] = *(const u16x8*)&Bh[(size_t)(bn + row) * K + (kb_) + cc * 8];         \
      if (PB) rBl[p] = *(const u16x8*)&Bl[(size_t)(bn + row) * K + (kb_) + cc * 8]; \
    }                                                                               \
  }
  LOADTILE(0)
  for (int kb = 0; kb < K; kb += 64) {
    __syncthreads();
#pragma unroll
    for (int p = 0; p < APT; ++p) {
      int idx = tid + p * 256;
      int row = idx >> 3, cc = idx & 7;
      int off = row * 64 + ((cc * 8) ^ ((row & 7) << 3));
      *(u16x8*)&AhS[off] = rAh[p];
      if (PA) *(u16x8*)&AlS[off] = rAl[p];
    }
#pragma unroll
    for (int p = 0; p < BPT; ++p) {
      int idx = tid + p * 256;
      int row = idx >> 3, cc = idx & 7;
      int off = row * 64 + ((cc * 8) ^ ((row & 7) << 3));
      *(u16x8*)&BhS[off] = rBh[p];
      if (PB) *(u16x8*)&BlS[off] = rBl[p];
    }
    if (kb + 64 < K) LOADTILE(kb + 64)
    __syncthreads();
    __builtin_amdgcn_s_setprio(1);
#pragma unroll
    for (int sl = 0; sl < 2; ++sl) {
      short8v fa[MF], fal[MF], fb[NF], fbl[NF];
      int kof = (l >> 4) * 8 + sl * 32;
#pragma unroll
      for (int m = 0; m < MF; ++m) {
        int row = wm + m * 16 + (l & 15);
        int off = row * 64 + (kof ^ ((row & 7) << 3));
        fa[m] = *(const short8v*)&AhS[off];
        if (PA) fal[m] = *(const short8v*)&AlS[off];
      }
#pragma unroll
      for (int n = 0; n < NF; ++n) {
        int row = wn + n * 16 + (l & 15);
        int off = row * 64 + (kof ^ ((row & 7) << 3));
        fb[n] = *(const short8v*)&BhS[off];
        if (PB) fbl[n] = *(const short8v*)&BlS[off];
      }
#pragma unroll
      for (int m = 0; m < MF; ++m)
#pragma unroll
        for (int n = 0; n < NF; ++n) {
          acc[m][n] = __builtin_amdgcn_mfma_f32_16x16x32_bf16(fa[m], fb[n], acc[m][n], 0, 0, 0);
          if (PA)
            acc[m][n] = __builtin_amdgcn_mfma_f32_16x16x32_bf16(fal[m], fb[n], acc[m][n], 0, 0, 0);
          if (PB)
            acc[m][n] = __builtin_amdgcn_mfma_f32_16x16x32_bf16(fa[m], fbl[n], acc[m][n], 0, 0, 0);
        }
    }
    __builtin_amdgcn_s_setprio(0);
  }
#undef LOADTILE
#pragma unroll
  for (int m = 0; m < MF; ++m)
#pragma unroll
    for (int n = 0; n < NF; ++n)
#pragma unroll
      for (int r = 0; r < 4; ++r) {
        int grow = bm + wm + m * 16 + (l >> 4) * 4 + r;
        int gcol = bn + wn + n * 16 + (l & 15);
        float v = acc[m][n][r];
        if (MODE == 0) {
          C[(size_t)grow * N + gcol] = v;
        } else if (MODE == 1) {
          u16 hb = f2bf(v);
          O1[(size_t)grow * N + gcol] = hb;
          O2[(size_t)grow * N + gcol] = f2bf(v - bf2f(hb));
        } else {
          int k = gcol & 31;
          int gp = (gcol & ~31) | (((k >> 2) & 3) << 3) |
                   (((k >> 4) & 1) << 2) | (k & 3);
          O1[(size_t)grow * N + gp] = f2bf(v);
        }
      }
}

// ---------------- MFMA causal GQA attention v7 (swapped, TK=64, 24KB, 4 waves/SIMD) ----------------
// Grid (32, H, B), qt = 31 - bx (largest first), nsteps = qt+1. 24KB LDS; launch_bounds(256,4)
// caps VGPR at 128 (measured need ~84 -> no spill, unlike r10's (256,6)->40 clamp).
// s = mfma(K, Q): lane holds S[key][q=l&15]; softmax lane-local + 2 shfl.
// PV = mfma(Vt, P-in-register). Oacc[d][q]. Epilogue transposes via freed LDS.
__global__ __launch_bounds__(256, 4) void attn_mfma7(
    const u16* __restrict__ Qh, const u16* __restrict__ Ql,
    const u16* __restrict__ Kh, const u16* __restrict__ Kl,
    const u16* __restrict__ Vt,
    const float* __restrict__ qk_gain,
    float* __restrict__ AO) {
  __shared__ __align__(16) u16 SM[12288];   // Kh 8K | Kl 8K | Vt 8K (24KB)
  u16* Kh_s = SM;
  u16* Kl_s = SM + 4096;
  u16* Vt_s = SM + 8192;
  int tid = threadIdx.x;
  int w = tid >> 6, l = tid & 63;
  int qt = 31 - (int)blockIdx.x;
  int q0 = qt * 64;
  int h = blockIdx.y, b = blockIdx.z;
  int kvh = h >> 2;
  const float sc2 = qk_gain[0] * 0.125f * 1.44269504f;   // v_exp_f32 computes 2^x
  // Q B-frags straight from global (col q = w*16 + (l&15))
  short8v qb_h[2], qb_l[2];
  {
    size_t qrow = (size_t)(b * Tc + q0 + w * 16 + (l & 15));
#pragma unroll
    for (int sl = 0; sl < 2; ++sl) {
      int dstart = (l >> 4) * 8 + sl * 32;
      qb_h[sl] = *(const short8v*)&Qh[qrow * Dc + h * 64 + dstart];
      qb_l[sl] = *(const short8v*)&Ql[qrow * Dc + h * 64 + dstart];
    }
  }
  f32x4 Oacc[4] = {{0,0,0,0},{0,0,0,0},{0,0,0,0},{0,0,0,0}};
  float mrow = -3.0e38f, lrow = 0.0f;
  int qmax_w = q0 + w * 16 + 15;
  int qg = q0 + w * 16 + (l & 15);
  int nsteps = qt + 1;
  u16x8 pk[2], pl[2], pv[2];
#define AISSUE3(K0)                                                             \
  {                                                                             \
    _Pragma("unroll") for (int p = 0; p < 2; ++p) {                             \
      int idx = tid + p * 256;                                                  \
      int jj = idx >> 3, cc = idx & 7;                                          \
      size_t kb = ((size_t)(b * Tc + (K0) + jj)) * (HKVc * HDc) + kvh * 64 + cc * 8; \
      pk[p] = *(const u16x8*)&Kh[kb];                                           \
      pl[p] = *(const u16x8*)&Kl[kb];                                           \
      size_t vb = ((size_t)(kvh * 64 + jj)) * (size_t)Mc + b * Tc + (K0) + cc * 8; \
      pv[p] = *(const u16x8*)&Vt[vb];                                           \
    }                                                                           \
  }
  AISSUE3(0)
  for (int stp = 0; stp < nsteps; ++stp) {
    int k0 = stp * 64;
    __syncthreads();
#pragma unroll
    for (int p = 0; p < 2; ++p) {
      int idx = tid + p * 256;
      int jj = idx >> 3, cc = idx & 7;
      int sw = jj * 64 + ((cc * 8) ^ ((jj & 7) << 3));
      *(u16x8*)&Kh_s[sw] = pk[p];
      *(u16x8*)&Kl_s[sw] = pl[p];
      *(u16x8*)&Vt_s[sw] = pv[p];
    }
    if (stp + 1 < nsteps) AISSUE3((stp + 1) * 64)
    __syncthreads();
    if (k0 > qmax_w) continue;   // fully masked for this wave (barriers done)
    // ---- QK^T swapped: s[kt] = K_tile x Q -> S[key][q=l&15] ----
    f32x4 s[4] = {{0,0,0,0},{0,0,0,0},{0,0,0,0},{0,0,0,0}};
    __builtin_amdgcn_s_setprio(1);
#pragma unroll
    for (int kt = 0; kt < 4; ++kt) {
      int key = kt * 16 + (l & 15);
#pragma unroll
      for (int sl = 0; sl < 2; ++sl) {
        int dstart = ((l >> 4) * 8 + 32 * sl) ^ ((key & 7) << 3);
        short8v bh = *(const short8v*)&Kh_s[key * 64 + dstart];
        short8v bl = *(const short8v*)&Kl_s[key * 64 + dstart];
        s[kt] = __builtin_amdgcn_mfma_f32_16x16x32_bf16(bh, qb_h[sl], s[kt], 0, 0, 0);
        s[kt] = __builtin_amdgcn_mfma_f32_16x16x32_bf16(bl, qb_h[sl], s[kt], 0, 0, 0);
        s[kt] = __builtin_amdgcn_mfma_f32_16x16x32_bf16(bh, qb_l[sl], s[kt], 0, 0, 0);
      }
    }
    __builtin_amdgcn_s_setprio(0);
    // ---- causal mask (lane-local; wave-uniform fast path) ----
    bool full = (k0 + 63) <= (q0 + w * 16);
    if (!full) {
#pragma unroll
      for (int kt = 0; kt < 4; ++kt)
#pragma unroll
        for (int r = 0; r < 4; ++r)
          if (k0 + kt * 16 + ((l >> 4) << 2) + r > qg) s[kt][r] = -3.0e38f;
    }
    // ---- softmax: 15 local fmax + 2 shfl ----
    float mk[4];
#pragma unroll
    for (int kt = 0; kt < 4; ++kt)
      mk[kt] = fmaxf(fmaxf(s[kt][0], s[kt][1]), fmaxf(s[kt][2], s[kt][3]));
    float mx = fmaxf(fmaxf(mk[0], mk[1]), fmaxf(mk[2], mk[3]));
    mx = fmaxf(mx, __shfl_xor(mx, 16));
    mx = fmaxf(mx, __shfl_xor(mx, 32));
    float mnew = fmaxf(mrow, mx);
    float msc = mnew * sc2;
    float corr = fast_exp2(__builtin_fmaf(mrow, sc2, -msc));
    mrow = mnew;
    float p[4][4];
    float sk[4];
#pragma unroll
    for (int kt = 0; kt < 4; ++kt) {
#pragma unroll
      for (int r = 0; r < 4; ++r)
        p[kt][r] = fast_exp2(__builtin_fmaf(s[kt][r], sc2, -msc));
      sk[kt] = (p[kt][0] + p[kt][1]) + (p[kt][2] + p[kt][3]);
    }
    float rs = (sk[0] + sk[1]) + (sk[2] + sk[3]);
    rs += __shfl_xor(rs, 16);
    rs += __shfl_xor(rs, 32);
    lrow = lrow * corr + rs;
#pragma unroll
    for (int dt = 0; dt < 4; ++dt) Oacc[dt] *= corr;
    // ---- pack P to bf16 B-frags entirely in-register (slot order = MODE 3 perm) ----
    short8v fbv[2];
#pragma unroll
    for (int sl = 0; sl < 2; ++sl) {
      union { u32 u[4]; short8v v; } fq;
      fq.u[0] = cvt_pk_bf16(p[2 * sl][0], p[2 * sl][1]);
      fq.u[1] = cvt_pk_bf16(p[2 * sl][2], p[2 * sl][3]);
      fq.u[2] = cvt_pk_bf16(p[2 * sl + 1][0], p[2 * sl + 1][1]);
      fq.u[3] = cvt_pk_bf16(p[2 * sl + 1][2], p[2 * sl + 1][3]);
      fbv[sl] = fq.v;
    }
    // ---- PV swapped: Oacc[d][q] += Vt x P ----
    __builtin_amdgcn_s_setprio(1);
#pragma unroll
    for (int dt = 0; dt < 4; ++dt) {
      int d = dt * 16 + (l & 15);
#pragma unroll
      for (int sl = 0; sl < 2; ++sl) {
        int kstart = ((l >> 4) * 8 + 32 * sl) ^ ((d & 7) << 3);
        short8v fav = *(const short8v*)&Vt_s[d * 64 + kstart];
        Oacc[dt] = __builtin_amdgcn_mfma_f32_16x16x32_bf16(fav, fbv[sl], Oacc[dt], 0, 0, 0);
      }
    }
    __builtin_amdgcn_s_setprio(0);
  }
  // ---- epilogue: transpose Oacc via freed LDS, coalesced AO store ----
  __syncthreads();   // all waves done reading K/V LDS
  float* Es = (float*)SM + w * (16 * 68);
  float invl = 1.0f / lrow;
#pragma unroll
  for (int dt = 0; dt < 4; ++dt)
#pragma unroll
    for (int r = 0; r < 4; ++r)
      Es[(l & 15) * 68 + dt * 16 + ((l >> 4) << 2) + r] = Oacc[dt][r] * invl;
  size_t arow = ((size_t)(b * Tc + q0 + w * 16 + (l >> 2))) * Dc + h * 64 + (l & 3) * 4;
#pragma unroll
  for (int j = 0; j < 4; ++j) {
    float4 vv = *(const float4*)&Es[(l >> 2) * 68 + (l & 3) * 4 + j * 16];
    *(float4*)&AO[arow + j * 16] = vv;
  }
}

// ---------------- launch ----------------
extern "C" void kernel_launch(void* const* d_in, const int* in_sizes, int n_in,
                              void* d_out, int out_size, void* d_ws, size_t ws_size,
                              hipStream_t stream) {
  const float* x    = (const float*)d_in[0];
  const float* q_w  = (const float*)d_in[1];
  const float* q_g  = (const float*)d_in[2];
  const float* k_w  = (const float*)d_in[3];
  const float* k_g  = (const float*)d_in[4];
  const float* v_w  = (const float*)d_in[5];
  const float* o_w  = (const float*)d_in[6];
  const float* o_g  = (const float*)d_in[7];
  const float* qk_g = (const float*)d_in[8];

  // workspace (bytes), peak ~61.2 MB
  char* base = (char*)d_ws;
  u16* Xqh = (u16*)(base + (0ull  << 20));   // 8MB
  u16* Xql = (u16*)(base + (8ull  << 20));   // 8MB
  u16* Xkh = (u16*)(base + (16ull << 20));   // 8MB
  u16* Xkl = (u16*)(base + (24ull << 20));   // 8MB
  u16* Xvh = (u16*)(base + (32ull << 20));   // 8MB
  u16* Xvl = (u16*)(base + (40ull << 20));   // 8MB (Ql overlay region only)
  u16* Kh  = (u16*)(base + (48ull << 20));   // 2MB
  u16* Kl  = (u16*)(base + (50ull << 20));   // 2MB
  u16* Vt  = (u16*)(base + (52ull << 20));   // 2MB  [256][4096], slot-permuted per 32
  u16* Wq  = (u16*)(base + (54ull << 20));   // 2MB
  u16* Wk  = (u16*)(base + (56ull << 20));   // 0.5MB
  u16* Wo  = (u16*)(base + (57ull << 20));   // 2MB
  u16* Vwh = (u16*)(base + (59ull << 20));   // 0.5MB
  float* leaf = (float*)(base + (61ull << 20)); // 18432 floats (Q 8192 | K 2048 | O 8192)
  float* th   = leaf + 18432;                // 3
  // overlays
  float* AO  = (float*)base;                 // 16MB over Xqh/Xql (dead after Q-proj)
  u16* Xoh = Xkh;                            // over Xk (dead after K-proj)
  u16* Qh  = Xvh; u16* Ql  = Xvl;            // over Xv region (Xvh dead after V-proj)

  // 1) numpy-exact fp32 thresholds
  np_leafsum_all<<<576, 256, 0, stream>>>(q_w, k_w, o_w, leaf);
  np_treemean3<<<3, 256, 0, stream>>>(leaf, th);

  // 2) quantize ternary weights -> bf16 + v_w bf16 cast (one launch)
  quant_split_all<<<2560, 256, 0, stream>>>(q_w, k_w, o_w, v_w, th, Wq, Wk, Wo, Vwh);

  // 3) RMSNorm(x) -> bf16 hi/lo (q,k gains) + raw-x bf16 (V path)
  rmsnorm_split6<<<Mc, 256, 0, stream>>>(x, q_g, k_g, Xqh, Xql, Xkh, Xkl, Xvh);

  // 4) projections (MFMA). V first (Q output overlays Xv).
  //    V: Vt[256][4096] = Vw @ x^T, SINGLE-pass bf16, slot-permuted cols. 64x64 tiles.
  gemm_mfma<false, false, 3, 2, 2><<<dim3(64, 4), 256, 0, stream>>>(
      Vwh, nullptr, Xvh, nullptr, 256, Mc, 1024, nullptr, Vt, nullptr);
  //    Q: 2-pass (A hi/lo), hi/lo bf16 out, 64x128 tiles.
  gemm_mfma<true, false, 1, 2, 4><<<dim3(8, 64), 256, 0, stream>>>(
      Xqh, Xql, Wq, nullptr, Mc, 1024, 1024, nullptr, Qh, Ql);
  //    K: 2-pass (A hi/lo), hi/lo bf16 out, 64x64 tiles.
  gemm_mfma<true, false, 1, 2, 2><<<dim3(4, 64), 256, 0, stream>>>(
      Xkh, Xkl, Wk, nullptr, Mc, 256, 1024, nullptr, Kh, Kl);

  // 5) MFMA causal GQA attention v7 -> AO fp32
  attn_mfma7<<<dim3(32, Hc, Bc), 256, 0, stream>>>(Qh, Ql, Kh, Kl, Vt, qk_g, AO);

  // 6) output bitlinear: single-pass bf16 A
  rmsnorm_split6<<<Mc, 256, 0, stream>>>(AO, o_g, nullptr, Xoh, nullptr, nullptr, nullptr,
                                         nullptr);
  gemm_mfma<false, false, 0, 2, 4><<<dim3(8, 64), 256, 0, stream>>>(
      Xoh, nullptr, Wo, nullptr, Mc, 1024, 1024, (float*)d_out, nullptr, nullptr);
}

// Round 13
// 151.733 us; speedup vs baseline: 2.0285x; 1.0940x over previous
//
#include <hip/hip_runtime.h>
#include <hip/hip_bf16.h>
#include <cstdint>
#include <cstddef>

typedef unsigned short u16;
typedef unsigned int u32;
typedef __attribute__((ext_vector_type(8))) short short8v;   // 8 bf16 MFMA frag
typedef __attribute__((ext_vector_type(4))) float f32x4;     // MFMA accumulator
typedef __attribute__((ext_vector_type(4))) u16 u16x4;
typedef __attribute__((ext_vector_type(8))) u16 u16x8;

// Problem constants
static constexpr int Bc = 2, Tc = 2048, Dc = 1024, Hc = 16, HKVc = 4, HDc = 64;
static constexpr int Mc = Bc * Tc;                 // 4096 rows
static constexpr float EPSc = 1.1920929e-07f;

static __device__ __forceinline__ u16 f2bf(float f) {
  u32 u = __builtin_bit_cast(u32, f);
  return (u16)((u + 0x7fffu + ((u >> 16) & 1u)) >> 16);
}
static __device__ __forceinline__ float bf2f(u16 b) {
  u32 u = ((u32)b) << 16;
  return __builtin_bit_cast(float, u);
}
static __device__ __forceinline__ float fast_exp2(float x) {
  float r;
  asm("v_exp_f32 %0, %1" : "=v"(r) : "v"(x));
  return r;
}
static __device__ __forceinline__ u32 cvt_pk_bf16(float lo, float hi) {
  u32 r;
  asm("v_cvt_pk_bf16_f32 %0, %1, %2" : "=v"(r) : "v"(lo), "v"(hi));
  return r;
}

// ---------------- numpy-exact fp32 pairwise abs-mean (verified round 3/7) ----------------
__global__ __launch_bounds__(256) void np_leafsum_all(const float* __restrict__ q_w,
                                                      const float* __restrict__ k_w,
                                                      const float* __restrict__ o_w,
                                                      float* __restrict__ leaf) {
  int blk = blockIdx.x;
  const float* w;
  float* out;
  int lfbase;
  if (blk < 256)      { w = q_w; out = leaf;         lfbase = blk * 32; }
  else if (blk < 320) { w = k_w; out = leaf + 8192;  lfbase = (blk - 256) * 32; }
  else                { w = o_w; out = leaf + 10240; lfbase = (blk - 320) * 32; }
  int t = threadIdx.x;
  int lf = lfbase + (t >> 3), j = t & 7;
  const float* a = w + (size_t)lf * 128;
  float r = fabsf(a[j]);
#pragma unroll
  for (int i = 8; i < 128; i += 8) r += fabsf(a[i + j]);
  float x = r + __shfl_xor(r, 1);
  float y = x + __shfl_xor(x, 2);
  float z = y + __shfl_xor(y, 4);
  if (j == 0) out[lf] = z;
}

__global__ __launch_bounds__(256) void np_treemean3(const float* __restrict__ leaf,
                                                    float* __restrict__ th) {
  int m = blockIdx.x;
  const float* src = leaf + (m == 0 ? 0 : (m == 1 ? 8192 : 10240));
  int nle = (m == 1) ? 2048 : 8192;
  float inv_n = (m == 1) ? (1.0f / 262144.0f) : (1.0f / 1048576.0f);
  int t = threadIdx.x;
  int chunk = nle >> 8;                      // 32 or 8, power of two
  float v[32];
  for (int i = 0; i < chunk; i += 4) {
    float4 f = *(const float4*)&src[t * chunk + i];
    v[i] = f.x; v[i + 1] = f.y; v[i + 2] = f.z; v[i + 3] = f.w;
  }
  for (int cnt = chunk >> 1; cnt >= 1; cnt >>= 1)
    for (int i = 0; i < cnt; ++i) v[i] = v[2 * i] + v[2 * i + 1];
  float s = v[0];
#pragma unroll
  for (int off = 1; off < 64; off <<= 1) s += __shfl_xor(s, off);
  __shared__ float red[4];
  if ((t & 63) == 0) red[t >> 6] = s;
  __syncthreads();
  if (t == 0) th[m] = ((red[0] + red[1]) + (red[2] + red[3])) * inv_n;
}

// ---------------- fused: ternary quantize (q/k/o) + v_w bf16 cast ----------------
__global__ __launch_bounds__(256) void quant_split_all(const float* __restrict__ q_w,
                                                       const float* __restrict__ k_w,
                                                       const float* __restrict__ o_w,
                                                       const float* __restrict__ v_w,
                                                       const float* __restrict__ th,
                                                       u16* __restrict__ Wq,
                                                       u16* __restrict__ Wk,
                                                       u16* __restrict__ Wo,
                                                       u16* __restrict__ Vwh) {
  int i4 = blockIdx.x * 256 + threadIdx.x;   // float4 index
  if (i4 < 589824) {
    const float* w; u16* o; float t;
    int j;
    if (i4 < 262144)      { w = q_w; o = Wq; t = th[0]; j = i4; }
    else if (i4 < 327680) { w = k_w; o = Wk; t = th[1]; j = i4 - 262144; }
    else                  { w = o_w; o = Wo; t = th[2]; j = i4 - 327680; }
    float4 v = *(const float4*)&w[(size_t)j * 4];
    float y[4] = {v.x, v.y, v.z, v.w};
    u16x4 q;
#pragma unroll
    for (int c = 0; c < 4; ++c)
      q[c] = (y[c] > t) ? (u16)0x3F80 : ((y[c] < -t) ? (u16)0xBF80 : (u16)0);
    *(u16x4*)&o[(size_t)j * 4] = q;
  } else {
    int j = i4 - 589824;                     // v_w float4 index, [0, 65536)
    float4 v = *(const float4*)&v_w[(size_t)j * 4];
    float y[4] = {v.x, v.y, v.z, v.w};
    u16x4 h;
#pragma unroll
    for (int c = 0; c < 4; ++c) h[c] = f2bf(y[c]);
    *(u16x4*)&Vwh[(size_t)j * 4] = h;
  }
}

// ---------------- RMSNorm -> bf16 (hi or hi/lo) x2 gains + raw-x bf16 ----------------
__global__ __launch_bounds__(256) void rmsnorm_split6(const float* __restrict__ X,
                                                      const float* __restrict__ g1,
                                                      const float* __restrict__ g2,
                                                      u16* __restrict__ H1, u16* __restrict__ L1,
                                                      u16* __restrict__ H2, u16* __restrict__ L2,
                                                      u16* __restrict__ HV) {
  int row = blockIdx.x;
  const float* xr = X + (size_t)row * Dc;
  int tid = threadIdx.x;
  float4 v = *(const float4*)&xr[tid * 4];
  float vv[4] = {v.x, v.y, v.z, v.w};
  if (HV != nullptr) {           // raw x bf16 for the single-pass V path
    u16x4 h;
#pragma unroll
    for (int j = 0; j < 4; ++j) h[j] = f2bf(vv[j]);
    *(u16x4*)&HV[(size_t)row * Dc + tid * 4] = h;
  }
  float ss = v.x * v.x + v.y * v.y + v.z * v.z + v.w * v.w;
#pragma unroll
  for (int off = 1; off < 64; off <<= 1) ss += __shfl_xor(ss, off);
  __shared__ float red[4];
  if ((tid & 63) == 0) red[tid >> 6] = ss;
  __syncthreads();
  float tot = red[0] + red[1] + red[2] + red[3];
  float inv = 1.0f / sqrtf(tot * (1.0f / (float)Dc) + EPSc);
  {
    float4 a = *(const float4*)&g1[tid * 4];
    float ga[4] = {a.x, a.y, a.z, a.w};
    u16x4 h, l;
#pragma unroll
    for (int j = 0; j < 4; ++j) {
      float y = vv[j] * inv * ga[j];
      u16 hb = f2bf(y);
      h[j] = hb;
      l[j] = f2bf(y - bf2f(hb));
    }
    *(u16x4*)&H1[(size_t)row * Dc + tid * 4] = h;
    if (L1 != nullptr) *(u16x4*)&L1[(size_t)row * Dc + tid * 4] = l;
  }
  if (g2 != nullptr) {
    float4 a = *(const float4*)&g2[tid * 4];
    float ga[4] = {a.x, a.y, a.z, a.w};
    u16x4 h, l;
#pragma unroll
    for (int j = 0; j < 4; ++j) {
      float y = vv[j] * inv * ga[j];
      u16 hb = f2bf(y);
      h[j] = hb;
      l[j] = f2bf(y - bf2f(hb));
    }
    *(u16x4*)&H2[(size_t)row * Dc + tid * 4] = h;
    if (L2 != nullptr) *(u16x4*)&L2[(size_t)row * Dc + tid * 4] = l;
  }
}

// ---------------- bf16 MFMA GEMM, templated tile + optional A-lo / B-lo passes ----------------
// MODE 0: C fp32.  MODE 1: O1/O2 = bf16 hi/lo.  MODE 3: O1 = bf16, cols permuted
// within each 32-block by gp(k) = (k&~31) | ((k>>2)&3)<<3 | ((k>>4)&1)<<2 | (k&3)
// (matches attn's in-register P slot order for the swapped-PV MFMA; verified r9-r12).
template <bool PA, bool PB, int MODE, int MF, int NF>
__global__ __launch_bounds__(256, 1) void gemm_mfma(
    const u16* __restrict__ Ah, const u16* __restrict__ Al,
    const u16* __restrict__ Bh, const u16* __restrict__ Bl,
    int M, int N, int K,
    float* __restrict__ C, u16* __restrict__ O1, u16* __restrict__ O2) {
  constexpr int BM = MF * 32, BN = NF * 32;
  constexpr int APT = BM / 32;               // u16x8 loads per thread for A tile
  constexpr int BPT = BN / 32;
  __shared__ __align__(16) u16 AhS[BM * 64];
  __shared__ __align__(16) u16 AlS[PA ? BM * 64 : 8];
  __shared__ __align__(16) u16 BhS[BN * 64];
  __shared__ __align__(16) u16 BlS[PB ? BN * 64 : 8];
  int tid = threadIdx.x;
  int l = tid & 63, w = tid >> 6;
  int wm = (w >> 1) * (BM / 2), wn = (w & 1) * (BN / 2);
  int bm = blockIdx.y * BM, bn = blockIdx.x * BN;
  u16x8 rAh[APT], rAl[PA ? APT : 1], rBh[BPT], rBl[PB ? BPT : 1];
  f32x4 acc[MF][NF] = {};
#define LOADTILE(kb_)                                                               \
  {                                                                                 \
    _Pragma("unroll") for (int p = 0; p < APT; ++p) {                               \
      int idx = tid + p * 256;                                                      \
      int row = idx >> 3, cc = idx & 7;                                             \
      rAh[p] = *(const u16x8*)&Ah[(size_t)(bm + row) * K + (kb_) + cc * 8];         \
      if (PA) rAl[p] = *(const u16x8*)&Al[(size_t)(bm + row) * K + (kb_) + cc * 8]; \
    }                                                                               \
    _Pragma("unroll") for (int p = 0; p < BPT; ++p) {                               \
      int idx = tid + p * 256;                                                      \
      int row = idx >> 3, cc = idx & 7;                                             \
      rBh[p] = *(const u16x8*)&Bh[(size_t)(bn + row) * K + (kb_) + cc * 8];         \
      if (PB) rBl[p] = *(const u16x8*)&Bl[(size_t)(bn + row) * K + (kb_) + cc * 8]; \
    }                                                                               \
  }
  LOADTILE(0)
  for (int kb = 0; kb < K; kb += 64) {
    __syncthreads();
#pragma unroll
    for (int p = 0; p < APT; ++p) {
      int idx = tid + p * 256;
      int row = idx >> 3, cc = idx & 7;
      int off = row * 64 + ((cc * 8) ^ ((row & 7) << 3));
      *(u16x8*)&AhS[off] = rAh[p];
      if (PA) *(u16x8*)&AlS[off] = rAl[p];
    }
#pragma unroll
    for (int p = 0; p < BPT; ++p) {
      int idx = tid + p * 256;
      int row = idx >> 3, cc = idx & 7;
      int off = row * 64 + ((cc * 8) ^ ((row & 7) << 3));
      *(u16x8*)&BhS[off] = rBh[p];
      if (PB) *(u16x8*)&BlS[off] = rBl[p];
    }
    if (kb + 64 < K) LOADTILE(kb + 64)
    __syncthreads();
    __builtin_amdgcn_s_setprio(1);
#pragma unroll
    for (int sl = 0; sl < 2; ++sl) {
      short8v fa[MF], fal[MF], fb[NF], fbl[NF];
      int kof = (l >> 4) * 8 + sl * 32;
#pragma unroll
      for (int m = 0; m < MF; ++m) {
        int row = wm + m * 16 + (l & 15);
        int off = row * 64 + (kof ^ ((row & 7) << 3));
        fa[m] = *(const short8v*)&AhS[off];
        if (PA) fal[m] = *(const short8v*)&AlS[off];
      }
#pragma unroll
      for (int n = 0; n < NF; ++n) {
        int row = wn + n * 16 + (l & 15);
        int off = row * 64 + (kof ^ ((row & 7) << 3));
        fb[n] = *(const short8v*)&BhS[off];
        if (PB) fbl[n] = *(const short8v*)&BlS[off];
      }
#pragma unroll
      for (int m = 0; m < MF; ++m)
#pragma unroll
        for (int n = 0; n < NF; ++n) {
          acc[m][n] = __builtin_amdgcn_mfma_f32_16x16x32_bf16(fa[m], fb[n], acc[m][n], 0, 0, 0);
          if (PA)
            acc[m][n] = __builtin_amdgcn_mfma_f32_16x16x32_bf16(fal[m], fb[n], acc[m][n], 0, 0, 0);
          if (PB)
            acc[m][n] = __builtin_amdgcn_mfma_f32_16x16x32_bf16(fa[m], fbl[n], acc[m][n], 0, 0, 0);
        }
    }
    __builtin_amdgcn_s_setprio(0);
  }
#undef LOADTILE
#pragma unroll
  for (int m = 0; m < MF; ++m)
#pragma unroll
    for (int n = 0; n < NF; ++n)
#pragma unroll
      for (int r = 0; r < 4; ++r) {
        int grow = bm + wm + m * 16 + (l >> 4) * 4 + r;
        int gcol = bn + wn + n * 16 + (l & 15);
        float v = acc[m][n][r];
        if (MODE == 0) {
          C[(size_t)grow * N + gcol] = v;
        } else if (MODE == 1) {
          u16 hb = f2bf(v);
          O1[(size_t)grow * N + gcol] = hb;
          O2[(size_t)grow * N + gcol] = f2bf(v - bf2f(hb));
        } else {
          int k = gcol & 31;
          int gp = (gcol & ~31) | (((k >> 2) & 3) << 3) |
                   (((k >> 4) & 1) << 2) | (k & 3);
          O1[(size_t)grow * N + gp] = f2bf(v);
        }
      }
}

// ---------------- MFMA causal GQA attention v8 ----------------
// Pair-in-block (qt = 31-pr then pr -> uniform 33 wall-steps, 512 blocks, 2/CU all-resident)
// + TK=64 DOUBLE-BUFFERED LDS (48KB): one barrier per step; ds_write of tile s+1 and
// global issue of tile s+2 overlap compute of tile s.  Swapped QK/PV (verified r9-r12).
__global__ __launch_bounds__(256, 2) void attn_mfma8(
    const u16* __restrict__ Qh, const u16* __restrict__ Ql,
    const u16* __restrict__ Kh, const u16* __restrict__ Kl,
    const u16* __restrict__ Vt,
    const float* __restrict__ qk_gain,
    float* __restrict__ AO) {
  __shared__ __align__(16) u16 SM[24576];   // 2 x (Kh 4096 | Kl 4096 | Vt 4096) u16 = 48KB
  int tid = threadIdx.x;
  int w = tid >> 6, l = tid & 63;
  int pr = blockIdx.x;                 // 0..15
  int h = blockIdx.y, b = blockIdx.z;
  int kvh = h >> 2;
  const float sc2 = qk_gain[0] * 0.125f * 1.44269504f;   // v_exp_f32 computes 2^x
  u16x8 pk[2], pl[2], pv[2];
#define AISSUE3(K0)                                                             \
  {                                                                             \
    _Pragma("unroll") for (int p = 0; p < 2; ++p) {                             \
      int idx = tid + p * 256;                                                  \
      int jj = idx >> 3, cc = idx & 7;                                          \
      size_t kb = ((size_t)(b * Tc + (K0) + jj)) * (HKVc * HDc) + kvh * 64 + cc * 8; \
      pk[p] = *(const u16x8*)&Kh[kb];                                           \
      pl[p] = *(const u16x8*)&Kl[kb];                                           \
      size_t vb = ((size_t)(kvh * 64 + jj)) * (size_t)Mc + b * Tc + (K0) + cc * 8; \
      pv[p] = *(const u16x8*)&Vt[vb];                                           \
    }                                                                           \
  }
#define WRITEBUF(BI)                                                            \
  {                                                                             \
    u16* bb = SM + (BI) * 12288;                                                \
    _Pragma("unroll") for (int p = 0; p < 2; ++p) {                             \
      int idx = tid + p * 256;                                                  \
      int jj = idx >> 3, cc = idx & 7;                                          \
      int sw = jj * 64 + ((cc * 8) ^ ((jj & 7) << 3));                          \
      *(u16x8*)&bb[sw] = pk[p];                                                 \
      *(u16x8*)&bb[4096 + sw] = pl[p];                                          \
      *(u16x8*)&bb[8192 + sw] = pv[p];                                          \
    }                                                                           \
  }
  for (int pass = 0; pass < 2; ++pass) {
    int qt = pass == 0 ? (31 - pr) : pr;
    int q0 = qt * 64;
    // Q B-frags straight from global (col q = w*16 + (l&15))
    short8v qb_h[2], qb_l[2];
    {
      size_t qrow = (size_t)(b * Tc + q0 + w * 16 + (l & 15));
#pragma unroll
      for (int sl = 0; sl < 2; ++sl) {
        int dstart = (l >> 4) * 8 + sl * 32;
        qb_h[sl] = *(const short8v*)&Qh[qrow * Dc + h * 64 + dstart];
        qb_l[sl] = *(const short8v*)&Ql[qrow * Dc + h * 64 + dstart];
      }
    }
    f32x4 Oacc[4] = {{0,0,0,0},{0,0,0,0},{0,0,0,0},{0,0,0,0}};
    float mrow = -3.0e38f, lrow = 0.0f;
    int qmax_w = q0 + w * 16 + 15;
    int qg = q0 + w * 16 + (l & 15);
    int nsteps = qt + 1;
    // ---- prologue: tile0 -> buf0, tile1 -> regs ----
    AISSUE3(0)
    __syncthreads();               // protect prev pass's LDS (Es / buffers)
    WRITEBUF(0)
    if (nsteps > 1) AISSUE3(64)
    __syncthreads();               // buf0 visible
    for (int stp = 0; stp < nsteps; ++stp) {
      int k0 = stp * 64;
      u16* Kh_s = SM + (stp & 1) * 12288;
      u16* Kl_s = Kh_s + 4096;
      u16* Vt_s = Kh_s + 8192;
      // pipeline: write tile s+1 to the other buffer; issue loads for tile s+2
      if (stp + 1 < nsteps) WRITEBUF((stp + 1) & 1)
      if (stp + 2 < nsteps) AISSUE3((stp + 2) * 64)
      if (k0 <= qmax_w) {
        // ---- QK^T swapped: s[kt] = K_tile x Q -> S[key][q=l&15] ----
        f32x4 s[4] = {{0,0,0,0},{0,0,0,0},{0,0,0,0},{0,0,0,0}};
        __builtin_amdgcn_s_setprio(1);
#pragma unroll
        for (int kt = 0; kt < 4; ++kt) {
          int key = kt * 16 + (l & 15);
#pragma unroll
          for (int sl = 0; sl < 2; ++sl) {
            int dstart = ((l >> 4) * 8 + 32 * sl) ^ ((key & 7) << 3);
            short8v bh = *(const short8v*)&Kh_s[key * 64 + dstart];
            short8v bl = *(const short8v*)&Kl_s[key * 64 + dstart];
            s[kt] = __builtin_amdgcn_mfma_f32_16x16x32_bf16(bh, qb_h[sl], s[kt], 0, 0, 0);
            s[kt] = __builtin_amdgcn_mfma_f32_16x16x32_bf16(bl, qb_h[sl], s[kt], 0, 0, 0);
            s[kt] = __builtin_amdgcn_mfma_f32_16x16x32_bf16(bh, qb_l[sl], s[kt], 0, 0, 0);
          }
        }
        __builtin_amdgcn_s_setprio(0);
        // ---- causal mask (lane-local; wave-uniform fast path) ----
        bool full = (k0 + 63) <= (q0 + w * 16);
        if (!full) {
#pragma unroll
          for (int kt = 0; kt < 4; ++kt)
#pragma unroll
            for (int r = 0; r < 4; ++r)
              if (k0 + kt * 16 + ((l >> 4) << 2) + r > qg) s[kt][r] = -3.0e38f;
        }
        // ---- softmax: 15 local fmax + 2 shfl ----
        float mk[4];
#pragma unroll
        for (int kt = 0; kt < 4; ++kt)
          mk[kt] = fmaxf(fmaxf(s[kt][0], s[kt][1]), fmaxf(s[kt][2], s[kt][3]));
        float mx = fmaxf(fmaxf(mk[0], mk[1]), fmaxf(mk[2], mk[3]));
        mx = fmaxf(mx, __shfl_xor(mx, 16));
        mx = fmaxf(mx, __shfl_xor(mx, 32));
        float mnew = fmaxf(mrow, mx);
        float msc = mnew * sc2;
        float corr = fast_exp2(__builtin_fmaf(mrow, sc2, -msc));
        mrow = mnew;
        float p[4][4];
        float sk[4];
#pragma unroll
        for (int kt = 0; kt < 4; ++kt) {
#pragma unroll
          for (int r = 0; r < 4; ++r)
            p[kt][r] = fast_exp2(__builtin_fmaf(s[kt][r], sc2, -msc));
          sk[kt] = (p[kt][0] + p[kt][1]) + (p[kt][2] + p[kt][3]);
        }
        float rs = (sk[0] + sk[1]) + (sk[2] + sk[3]);
        rs += __shfl_xor(rs, 16);
        rs += __shfl_xor(rs, 32);
        lrow = lrow * corr + rs;
#pragma unroll
        for (int dt = 0; dt < 4; ++dt) Oacc[dt] *= corr;
        // ---- pack P to bf16 B-frags entirely in-register (slot order = MODE 3 perm) ----
        short8v fbv[2];
#pragma unroll
        for (int sl = 0; sl < 2; ++sl) {
          union { u32 u[4]; short8v v; } fq;
          fq.u[0] = cvt_pk_bf16(p[2 * sl][0], p[2 * sl][1]);
          fq.u[1] = cvt_pk_bf16(p[2 * sl][2], p[2 * sl][3]);
          fq.u[2] = cvt_pk_bf16(p[2 * sl + 1][0], p[2 * sl + 1][1]);
          fq.u[3] = cvt_pk_bf16(p[2 * sl + 1][2], p[2 * sl + 1][3]);
          fbv[sl] = fq.v;
        }
        // ---- PV swapped: Oacc[d][q] += Vt x P ----
        __builtin_amdgcn_s_setprio(1);
#pragma unroll
        for (int dt = 0; dt < 4; ++dt) {
          int d = dt * 16 + (l & 15);
#pragma unroll
          for (int sl = 0; sl < 2; ++sl) {
            int kstart = ((l >> 4) * 8 + 32 * sl) ^ ((d & 7) << 3);
            short8v fav = *(const short8v*)&Vt_s[d * 64 + kstart];
            Oacc[dt] = __builtin_amdgcn_mfma_f32_16x16x32_bf16(fav, fbv[sl], Oacc[dt], 0, 0, 0);
          }
        }
        __builtin_amdgcn_s_setprio(0);
      }
      __syncthreads();             // single barrier: writes visible, reads done
    }
    // ---- epilogue: transpose Oacc via LDS scratch, coalesced AO store ----
    // (last loop iteration ended with a barrier; Es writes/reads are intra-wave;
    //  next pass's prologue barrier protects Es before buf0 is overwritten)
    float* Es = (float*)SM + w * (16 * 68);
    float invl = 1.0f / lrow;
#pragma unroll
    for (int dt = 0; dt < 4; ++dt)
#pragma unroll
      for (int r = 0; r < 4; ++r)
        Es[(l & 15) * 68 + dt * 16 + ((l >> 4) << 2) + r] = Oacc[dt][r] * invl;
    size_t arow = ((size_t)(b * Tc + q0 + w * 16 + (l >> 2))) * Dc + h * 64 + (l & 3) * 4;
#pragma unroll
    for (int j = 0; j < 4; ++j) {
      float4 vv = *(const float4*)&Es[(l >> 2) * 68 + (l & 3) * 4 + j * 16];
      *(float4*)&AO[arow + j * 16] = vv;
    }
  }
#undef AISSUE3
#undef WRITEBUF
}

// ---------------- launch ----------------
extern "C" void kernel_launch(void* const* d_in, const int* in_sizes, int n_in,
                              void* d_out, int out_size, void* d_ws, size_t ws_size,
                              hipStream_t stream) {
  const float* x    = (const float*)d_in[0];
  const float* q_w  = (const float*)d_in[1];
  const float* q_g  = (const float*)d_in[2];
  const float* k_w  = (const float*)d_in[3];
  const float* k_g  = (const float*)d_in[4];
  const float* v_w  = (const float*)d_in[5];
  const float* o_w  = (const float*)d_in[6];
  const float* o_g  = (const float*)d_in[7];
  const float* qk_g = (const float*)d_in[8];

  // workspace (bytes), peak ~61.2 MB
  char* base = (char*)d_ws;
  u16* Xqh = (u16*)(base + (0ull  << 20));   // 8MB
  u16* Xql = (u16*)(base + (8ull  << 20));   // 8MB
  u16* Xkh = (u16*)(base + (16ull << 20));   // 8MB
  u16* Xkl = (u16*)(base + (24ull << 20));   // 8MB
  u16* Xvh = (u16*)(base + (32ull << 20));   // 8MB
  u16* Xvl = (u16*)(base + (40ull << 20));   // 8MB (Ql overlay region only)
  u16* Kh  = (u16*)(base + (48ull << 20));   // 2MB
  u16* Kl  = (u16*)(base + (50ull << 20));   // 2MB
  u16* Vt  = (u16*)(base + (52ull << 20));   // 2MB  [256][4096], slot-permuted per 32
  u16* Wq  = (u16*)(base + (54ull << 20));   // 2MB
  u16* Wk  = (u16*)(base + (56ull << 20));   // 0.5MB
  u16* Wo  = (u16*)(base + (57ull << 20));   // 2MB
  u16* Vwh = (u16*)(base + (59ull << 20));   // 0.5MB
  float* leaf = (float*)(base + (61ull << 20)); // 18432 floats (Q 8192 | K 2048 | O 8192)
  float* th   = leaf + 18432;                // 3
  // overlays
  float* AO  = (float*)base;                 // 16MB over Xqh/Xql (dead after Q-proj)
  u16* Xoh = Xkh;                            // over Xk (dead after K-proj)
  u16* Qh  = Xvh; u16* Ql  = Xvl;            // over Xv region (Xvh dead after V-proj)

  // 1) numpy-exact fp32 thresholds
  np_leafsum_all<<<576, 256, 0, stream>>>(q_w, k_w, o_w, leaf);
  np_treemean3<<<3, 256, 0, stream>>>(leaf, th);

  // 2) quantize ternary weights -> bf16 + v_w bf16 cast (one launch)
  quant_split_all<<<2560, 256, 0, stream>>>(q_w, k_w, o_w, v_w, th, Wq, Wk, Wo, Vwh);

  // 3) RMSNorm(x) -> bf16 hi/lo (q,k gains) + raw-x bf16 (V path)
  rmsnorm_split6<<<Mc, 256, 0, stream>>>(x, q_g, k_g, Xqh, Xql, Xkh, Xkl, Xvh);

  // 4) projections (MFMA). V first (Q output overlays Xv).
  //    V: Vt[256][4096] = Vw @ x^T, SINGLE-pass bf16, slot-permuted cols. 64x64 tiles.
  gemm_mfma<false, false, 3, 2, 2><<<dim3(64, 4), 256, 0, stream>>>(
      Vwh, nullptr, Xvh, nullptr, 256, Mc, 1024, nullptr, Vt, nullptr);
  //    Q: 2-pass (A hi/lo), hi/lo bf16 out, 64x128 tiles.
  gemm_mfma<true, false, 1, 2, 4><<<dim3(8, 64), 256, 0, stream>>>(
      Xqh, Xql, Wq, nullptr, Mc, 1024, 1024, nullptr, Qh, Ql);
  //    K: 2-pass (A hi/lo), hi/lo bf16 out, 64x64 tiles.
  gemm_mfma<true, false, 1, 2, 2><<<dim3(4, 64), 256, 0, stream>>>(
      Xkh, Xkl, Wk, nullptr, Mc, 256, 1024, nullptr, Kh, Kl);

  // 5) MFMA causal GQA attention v8 -> AO fp32
  attn_mfma8<<<dim3(16, Hc, Bc), 256, 0, stream>>>(Qh, Ql, Kh, Kl, Vt, qk_g, AO);

  // 6) output bitlinear: single-pass bf16 A
  rmsnorm_split6<<<Mc, 256, 0, stream>>>(AO, o_g, nullptr, Xoh, nullptr, nullptr, nullptr,
                                         nullptr);
  gemm_mfma<false, false, 0, 2, 4><<<dim3(8, 64), 256, 0, stream>>>(
      Xoh, nullptr, Wo, nullptr, Mc, 1024, 1024, (float*)d_out, nullptr, nullptr);
}

// Round 14
// 149.693 us; speedup vs baseline: 2.0561x; 1.0136x over previous
//
#include <hip/hip_runtime.h>
#include <hip/hip_bf16.h>
#include <cstdint>
#include <cstddef>

typedef unsigned short u16;
typedef unsigned int u32;
typedef __attribute__((ext_vector_type(8))) short short8v;   // 8 bf16 MFMA frag
typedef __attribute__((ext_vector_type(4))) float f32x4;     // MFMA accumulator
typedef __attribute__((ext_vector_type(4))) u16 u16x4;
typedef __attribute__((ext_vector_type(8))) u16 u16x8;

// Problem constants
static constexpr int Bc = 2, Tc = 2048, Dc = 1024, Hc = 16, HKVc = 4, HDc = 64;
static constexpr int Mc = Bc * Tc;                 // 4096 rows
static constexpr float EPSc = 1.1920929e-07f;

static __device__ __forceinline__ u16 f2bf(float f) {
  u32 u = __builtin_bit_cast(u32, f);
  return (u16)((u + 0x7fffu + ((u >> 16) & 1u)) >> 16);
}
static __device__ __forceinline__ float bf2f(u16 b) {
  u32 u = ((u32)b) << 16;
  return __builtin_bit_cast(float, u);
}
static __device__ __forceinline__ float fast_exp2(float x) {
  float r;
  asm("v_exp_f32 %0, %1" : "=v"(r) : "v"(x));
  return r;
}
static __device__ __forceinline__ u32 cvt_pk_bf16(float lo, float hi) {
  u32 r;
  asm("v_cvt_pk_bf16_f32 %0, %1, %2" : "=v"(r) : "v"(lo), "v"(hi));
  return r;
}

// ---------------- numpy-exact fp32 pairwise abs-mean (verified round 3/7) ----------------
__global__ __launch_bounds__(256) void np_leafsum_all(const float* __restrict__ q_w,
                                                      const float* __restrict__ k_w,
                                                      const float* __restrict__ o_w,
                                                      float* __restrict__ leaf) {
  int blk = blockIdx.x;
  const float* w;
  float* out;
  int lfbase;
  if (blk < 256)      { w = q_w; out = leaf;         lfbase = blk * 32; }
  else if (blk < 320) { w = k_w; out = leaf + 8192;  lfbase = (blk - 256) * 32; }
  else                { w = o_w; out = leaf + 10240; lfbase = (blk - 320) * 32; }
  int t = threadIdx.x;
  int lf = lfbase + (t >> 3), j = t & 7;
  const float* a = w + (size_t)lf * 128;
  float r = fabsf(a[j]);
#pragma unroll
  for (int i = 8; i < 128; i += 8) r += fabsf(a[i + j]);
  float x = r + __shfl_xor(r, 1);
  float y = x + __shfl_xor(x, 2);
  float z = y + __shfl_xor(y, 4);
  if (j == 0) out[lf] = z;
}

__global__ __launch_bounds__(256) void np_treemean3(const float* __restrict__ leaf,
                                                    float* __restrict__ th) {
  int m = blockIdx.x;
  const float* src = leaf + (m == 0 ? 0 : (m == 1 ? 8192 : 10240));
  int nle = (m == 1) ? 2048 : 8192;
  float inv_n = (m == 1) ? (1.0f / 262144.0f) : (1.0f / 1048576.0f);
  int t = threadIdx.x;
  int chunk = nle >> 8;                      // 32 or 8, power of two
  float v[32];
  for (int i = 0; i < chunk; i += 4) {
    float4 f = *(const float4*)&src[t * chunk + i];
    v[i] = f.x; v[i + 1] = f.y; v[i + 2] = f.z; v[i + 3] = f.w;
  }
  for (int cnt = chunk >> 1; cnt >= 1; cnt >>= 1)
    for (int i = 0; i < cnt; ++i) v[i] = v[2 * i] + v[2 * i + 1];
  float s = v[0];
#pragma unroll
  for (int off = 1; off < 64; off <<= 1) s += __shfl_xor(s, off);
  __shared__ float red[4];
  if ((t & 63) == 0) red[t >> 6] = s;
  __syncthreads();
  if (t == 0) th[m] = ((red[0] + red[1]) + (red[2] + red[3])) * inv_n;
}

// ---------------- fused: ternary quantize (q/k/o) + v_w bf16 cast ----------------
__global__ __launch_bounds__(256) void quant_split_all(const float* __restrict__ q_w,
                                                       const float* __restrict__ k_w,
                                                       const float* __restrict__ o_w,
                                                       const float* __restrict__ v_w,
                                                       const float* __restrict__ th,
                                                       u16* __restrict__ Wq,
                                                       u16* __restrict__ Wk,
                                                       u16* __restrict__ Wo,
                                                       u16* __restrict__ Vwh) {
  int i4 = blockIdx.x * 256 + threadIdx.x;   // float4 index
  if (i4 < 589824) {
    const float* w; u16* o; float t;
    int j;
    if (i4 < 262144)      { w = q_w; o = Wq; t = th[0]; j = i4; }
    else if (i4 < 327680) { w = k_w; o = Wk; t = th[1]; j = i4 - 262144; }
    else                  { w = o_w; o = Wo; t = th[2]; j = i4 - 327680; }
    float4 v = *(const float4*)&w[(size_t)j * 4];
    float y[4] = {v.x, v.y, v.z, v.w};
    u16x4 q;
#pragma unroll
    for (int c = 0; c < 4; ++c)
      q[c] = (y[c] > t) ? (u16)0x3F80 : ((y[c] < -t) ? (u16)0xBF80 : (u16)0);
    *(u16x4*)&o[(size_t)j * 4] = q;
  } else {
    int j = i4 - 589824;                     // v_w float4 index, [0, 65536)
    float4 v = *(const float4*)&v_w[(size_t)j * 4];
    float y[4] = {v.x, v.y, v.z, v.w};
    u16x4 h;
#pragma unroll
    for (int c = 0; c < 4; ++c) h[c] = f2bf(y[c]);
    *(u16x4*)&Vwh[(size_t)j * 4] = h;
  }
}

// ---------------- RMSNorm -> bf16 (hi or hi/lo) x2 gains + raw-x bf16 ----------------
__global__ __launch_bounds__(256) void rmsnorm_split6(const float* __restrict__ X,
                                                      const float* __restrict__ g1,
                                                      const float* __restrict__ g2,
                                                      u16* __restrict__ H1, u16* __restrict__ L1,
                                                      u16* __restrict__ H2, u16* __restrict__ L2,
                                                      u16* __restrict__ HV) {
  int row = blockIdx.x;
  const float* xr = X + (size_t)row * Dc;
  int tid = threadIdx.x;
  float4 v = *(const float4*)&xr[tid * 4];
  float vv[4] = {v.x, v.y, v.z, v.w};
  if (HV != nullptr) {           // raw x bf16 for the single-pass V path
    u16x4 h;
#pragma unroll
    for (int j = 0; j < 4; ++j) h[j] = f2bf(vv[j]);
    *(u16x4*)&HV[(size_t)row * Dc + tid * 4] = h;
  }
  float ss = v.x * v.x + v.y * v.y + v.z * v.z + v.w * v.w;
#pragma unroll
  for (int off = 1; off < 64; off <<= 1) ss += __shfl_xor(ss, off);
  __shared__ float red[4];
  if ((tid & 63) == 0) red[tid >> 6] = ss;
  __syncthreads();
  float tot = red[0] + red[1] + red[2] + red[3];
  float inv = 1.0f / sqrtf(tot * (1.0f / (float)Dc) + EPSc);
  {
    float4 a = *(const float4*)&g1[tid * 4];
    float ga[4] = {a.x, a.y, a.z, a.w};
    u16x4 h, l;
#pragma unroll
    for (int j = 0; j < 4; ++j) {
      float y = vv[j] * inv * ga[j];
      u16 hb = f2bf(y);
      h[j] = hb;
      l[j] = f2bf(y - bf2f(hb));
    }
    *(u16x4*)&H1[(size_t)row * Dc + tid * 4] = h;
    if (L1 != nullptr) *(u16x4*)&L1[(size_t)row * Dc + tid * 4] = l;
  }
  if (g2 != nullptr) {
    float4 a = *(const float4*)&g2[tid * 4];
    float ga[4] = {a.x, a.y, a.z, a.w};
    u16x4 h, l;
#pragma unroll
    for (int j = 0; j < 4; ++j) {
      float y = vv[j] * inv * ga[j];
      u16 hb = f2bf(y);
      h[j] = hb;
      l[j] = f2bf(y - bf2f(hb));
    }
    *(u16x4*)&H2[(size_t)row * Dc + tid * 4] = h;
    if (L2 != nullptr) *(u16x4*)&L2[(size_t)row * Dc + tid * 4] = l;
  }
}

// ---------------- bf16 MFMA GEMM, templated tile + optional A-lo / B-lo passes ----------------
// MODE 0: C fp32.  MODE 1: O1/O2 = bf16 hi/lo.  MODE 3: O1 = bf16, cols permuted
// within each 32-block by gp(k) = (k&~31) | ((k>>2)&3)<<3 | ((k>>4)&1)<<2 | (k&3)
// (matches attn's in-register P slot order for the swapped-PV MFMA; verified r9-r13).
template <bool PA, bool PB, int MODE, int MF, int NF>
__global__ __launch_bounds__(256, 1) void gemm_mfma(
    const u16* __restrict__ Ah, const u16* __restrict__ Al,
    const u16* __restrict__ Bh, const u16* __restrict__ Bl,
    int M, int N, int K,
    float* __restrict__ C, u16* __restrict__ O1, u16* __restrict__ O2) {
  constexpr int BM = MF * 32, BN = NF * 32;
  constexpr int APT = BM / 32;               // u16x8 loads per thread for A tile
  constexpr int BPT = BN / 32;
  __shared__ __align__(16) u16 AhS[BM * 64];
  __shared__ __align__(16) u16 AlS[PA ? BM * 64 : 8];
  __shared__ __align__(16) u16 BhS[BN * 64];
  __shared__ __align__(16) u16 BlS[PB ? BN * 64 : 8];
  int tid = threadIdx.x;
  int l = tid & 63, w = tid >> 6;
  int wm = (w >> 1) * (BM / 2), wn = (w & 1) * (BN / 2);
  int bm = blockIdx.y * BM, bn = blockIdx.x * BN;
  u16x8 rAh[APT], rAl[PA ? APT : 1], rBh[BPT], rBl[PB ? BPT : 1];
  f32x4 acc[MF][NF] = {};
#define LOADTILE(kb_)                                                               \
  {                                                                                 \
    _Pragma("unroll") for (int p = 0; p < APT; ++p) {                               \
      int idx = tid + p * 256;                                                      \
      int row = idx >> 3, cc = idx & 7;                                             \
      rAh[p] = *(const u16x8*)&Ah[(size_t)(bm + row) * K + (kb_) + cc * 8];         \
      if (PA) rAl[p] = *(const u16x8*)&Al[(size_t)(bm + row) * K + (kb_) + cc * 8]; \
    }                                                                               \
    _Pragma("unroll") for (int p = 0; p < BPT; ++p) {                               \
      int idx = tid + p * 256;                                                      \
      int row = idx >> 3, cc = idx & 7;                                             \
      rBh[p] = *(const u16x8*)&Bh[(size_t)(bn + row) * K + (kb_) + cc * 8];         \
      if (PB) rBl[p] = *(const u16x8*)&Bl[(size_t)(bn + row) * K + (kb_) + cc * 8]; \
    }                                                                               \
  }
  LOADTILE(0)
  for (int kb = 0; kb < K; kb += 64) {
    __syncthreads();
#pragma unroll
    for (int p = 0; p < APT; ++p) {
      int idx = tid + p * 256;
      int row = idx >> 3, cc = idx & 7;
      int off = row * 64 + ((cc * 8) ^ ((row & 7) << 3));
      *(u16x8*)&AhS[off] = rAh[p];
      if (PA) *(u16x8*)&AlS[off] = rAl[p];
    }
#pragma unroll
    for (int p = 0; p < BPT; ++p) {
      int idx = tid + p * 256;
      int row = idx >> 3, cc = idx & 7;
      int off = row * 64 + ((cc * 8) ^ ((row & 7) << 3));
      *(u16x8*)&BhS[off] = rBh[p];
      if (PB) *(u16x8*)&BlS[off] = rBl[p];
    }
    if (kb + 64 < K) LOADTILE(kb + 64)
    __syncthreads();
    __builtin_amdgcn_s_setprio(1);
#pragma unroll
    for (int sl = 0; sl < 2; ++sl) {
      short8v fa[MF], fal[MF], fb[NF], fbl[NF];
      int kof = (l >> 4) * 8 + sl * 32;
#pragma unroll
      for (int m = 0; m < MF; ++m) {
        int row = wm + m * 16 + (l & 15);
        int off = row * 64 + (kof ^ ((row & 7) << 3));
        fa[m] = *(const short8v*)&AhS[off];
        if (PA) fal[m] = *(const short8v*)&AlS[off];
      }
#pragma unroll
      for (int n = 0; n < NF; ++n) {
        int row = wn + n * 16 + (l & 15);
        int off = row * 64 + (kof ^ ((row & 7) << 3));
        fb[n] = *(const short8v*)&BhS[off];
        if (PB) fbl[n] = *(const short8v*)&BlS[off];
      }
#pragma unroll
      for (int m = 0; m < MF; ++m)
#pragma unroll
        for (int n = 0; n < NF; ++n) {
          acc[m][n] = __builtin_amdgcn_mfma_f32_16x16x32_bf16(fa[m], fb[n], acc[m][n], 0, 0, 0);
          if (PA)
            acc[m][n] = __builtin_amdgcn_mfma_f32_16x16x32_bf16(fal[m], fb[n], acc[m][n], 0, 0, 0);
          if (PB)
            acc[m][n] = __builtin_amdgcn_mfma_f32_16x16x32_bf16(fa[m], fbl[n], acc[m][n], 0, 0, 0);
        }
    }
    __builtin_amdgcn_s_setprio(0);
  }
#undef LOADTILE
#pragma unroll
  for (int m = 0; m < MF; ++m)
#pragma unroll
    for (int n = 0; n < NF; ++n)
#pragma unroll
      for (int r = 0; r < 4; ++r) {
        int grow = bm + wm + m * 16 + (l >> 4) * 4 + r;
        int gcol = bn + wn + n * 16 + (l & 15);
        float v = acc[m][n][r];
        if (MODE == 0) {
          C[(size_t)grow * N + gcol] = v;
        } else if (MODE == 1) {
          u16 hb = f2bf(v);
          O1[(size_t)grow * N + gcol] = hb;
          O2[(size_t)grow * N + gcol] = f2bf(v - bf2f(hb));
        } else {
          int k = gcol & 31;
          int gp = (gcol & ~31) | (((k >> 2) & 3) << 3) |
                   (((k >> 4) & 1) << 2) | (k & 3);
          O1[(size_t)grow * N + gp] = f2bf(v);
        }
      }
}

// ---------------- MFMA causal GQA attention v9 (32 q-cols per wave) ----------------
// QBLK=128/block (4 waves x 32q): the 16 K-reads + 8 V-reads per wave-step now feed
// 64 MFMAs (was 32) -> LDS bytes per unit work HALVED (r13 diagnosis: ~half LDS-BW-bound).
// TK=64 double-buffered (48KB), one barrier/step. Grid (32 hb, 16 y): qt = y<8 ? 15-y : y-8
// so CU pair (i, i+256) gets complementary tiles (steps sum = 34, uniform).
__global__ __launch_bounds__(256, 2) void attn_mfma9(
    const u16* __restrict__ Qh, const u16* __restrict__ Ql,
    const u16* __restrict__ Kh, const u16* __restrict__ Kl,
    const u16* __restrict__ Vt,
    const float* __restrict__ qk_gain,
    float* __restrict__ AO) {
  __shared__ __align__(16) u16 SM[24576];   // 2 x (Kh 4096 | Kl 4096 | Vt 4096) u16 = 48KB
  int tid = threadIdx.x;
  int w = tid >> 6, l = tid & 63;
  int h = blockIdx.x & 15, b = blockIdx.x >> 4;
  int by = blockIdx.y;
  int qt = (by < 8) ? (15 - by) : (by - 8);   // largest tiles dispatch first
  int q0 = qt * 128;
  int kvh = h >> 2;
  const float sc2 = qk_gain[0] * 0.125f * 1.44269504f;   // v_exp_f32 computes 2^x
  u16x8 pk[2], pl[2], pv[2];
#define AISSUE3(K0)                                                             \
  {                                                                             \
    _Pragma("unroll") for (int p = 0; p < 2; ++p) {                             \
      int idx = tid + p * 256;                                                  \
      int jj = idx >> 3, cc = idx & 7;                                          \
      size_t kb = ((size_t)(b * Tc + (K0) + jj)) * (HKVc * HDc) + kvh * 64 + cc * 8; \
      pk[p] = *(const u16x8*)&Kh[kb];                                           \
      pl[p] = *(const u16x8*)&Kl[kb];                                           \
      size_t vb = ((size_t)(kvh * 64 + jj)) * (size_t)Mc + b * Tc + (K0) + cc * 8; \
      pv[p] = *(const u16x8*)&Vt[vb];                                           \
    }                                                                           \
  }
#define WRITEBUF(BI)                                                            \
  {                                                                             \
    u16* bb = SM + (BI) * 12288;                                                \
    _Pragma("unroll") for (int p = 0; p < 2; ++p) {                             \
      int idx = tid + p * 256;                                                  \
      int jj = idx >> 3, cc = idx & 7;                                          \
      int sw = jj * 64 + ((cc * 8) ^ ((jj & 7) << 3));                          \
      *(u16x8*)&bb[sw] = pk[p];                                                 \
      *(u16x8*)&bb[4096 + sw] = pl[p];                                          \
      *(u16x8*)&bb[8192 + sw] = pv[p];                                          \
    }                                                                           \
  }
  // Q B-frags straight from global: wave covers q-cols [w*32, w*32+32), 2 frags of 16
  short8v qb_h[4], qb_l[4];   // [q'*2 + sl]
#pragma unroll
  for (int qp = 0; qp < 2; ++qp) {
    size_t qrow = (size_t)(b * Tc + q0 + w * 32 + qp * 16 + (l & 15));
#pragma unroll
    for (int sl = 0; sl < 2; ++sl) {
      int dstart = (l >> 4) * 8 + sl * 32;
      qb_h[qp * 2 + sl] = *(const short8v*)&Qh[qrow * Dc + h * 64 + dstart];
      qb_l[qp * 2 + sl] = *(const short8v*)&Ql[qrow * Dc + h * 64 + dstart];
    }
  }
  f32x4 Oacc[8] = {{0,0,0,0},{0,0,0,0},{0,0,0,0},{0,0,0,0},
                   {0,0,0,0},{0,0,0,0},{0,0,0,0},{0,0,0,0}};   // [q'*4 + dt]
  float mrow[2] = {-3.0e38f, -3.0e38f};
  float lrow[2] = {0.f, 0.f};
  int qmax_w = q0 + w * 32 + 31;
  int nsteps = 2 * qt + 2;
  // ---- prologue: tile0 -> buf0, tile1 -> regs ----
  AISSUE3(0)
  WRITEBUF(0)
  AISSUE3(64)
  __syncthreads();               // buf0 visible
  for (int stp = 0; stp < nsteps; ++stp) {
    int k0 = stp * 64;
    u16* Kh_s = SM + (stp & 1) * 12288;
    u16* Kl_s = Kh_s + 4096;
    u16* Vt_s = Kh_s + 8192;
    // pipeline: write tile s+1 to the other buffer; issue loads for tile s+2
    if (stp + 1 < nsteps) WRITEBUF((stp + 1) & 1)
    if (stp + 2 < nsteps) AISSUE3((stp + 2) * 64)
    if (k0 <= qmax_w) {
      // ---- QK^T swapped: s = K_tile x Q -> S[key][q]; 16 ds_read feed 48 MFMA ----
      f32x4 s[8] = {{0,0,0,0},{0,0,0,0},{0,0,0,0},{0,0,0,0},
                    {0,0,0,0},{0,0,0,0},{0,0,0,0},{0,0,0,0}};   // [q'*4 + kt]
      __builtin_amdgcn_s_setprio(1);
#pragma unroll
      for (int kt = 0; kt < 4; ++kt) {
        int key = kt * 16 + (l & 15);
#pragma unroll
        for (int sl = 0; sl < 2; ++sl) {
          int dstart = ((l >> 4) * 8 + 32 * sl) ^ ((key & 7) << 3);
          short8v bh = *(const short8v*)&Kh_s[key * 64 + dstart];
          short8v bl = *(const short8v*)&Kl_s[key * 64 + dstart];
#pragma unroll
          for (int qp = 0; qp < 2; ++qp) {
            s[qp * 4 + kt] = __builtin_amdgcn_mfma_f32_16x16x32_bf16(bh, qb_h[qp * 2 + sl], s[qp * 4 + kt], 0, 0, 0);
            s[qp * 4 + kt] = __builtin_amdgcn_mfma_f32_16x16x32_bf16(bl, qb_h[qp * 2 + sl], s[qp * 4 + kt], 0, 0, 0);
            s[qp * 4 + kt] = __builtin_amdgcn_mfma_f32_16x16x32_bf16(bh, qb_l[qp * 2 + sl], s[qp * 4 + kt], 0, 0, 0);
          }
        }
      }
      __builtin_amdgcn_s_setprio(0);
      // ---- causal mask (lane-local; wave-uniform fast path) ----
      bool full = (k0 + 63) <= (q0 + w * 32);
      if (!full) {
#pragma unroll
        for (int qp = 0; qp < 2; ++qp) {
          int qg = q0 + w * 32 + qp * 16 + (l & 15);
#pragma unroll
          for (int kt = 0; kt < 4; ++kt)
#pragma unroll
            for (int r = 0; r < 4; ++r)
              if (k0 + kt * 16 + ((l >> 4) << 2) + r > qg) s[qp * 4 + kt][r] = -3.0e38f;
        }
      }
      // ---- softmax per q'-group: 15 local fmax + 2 shfl ----
      float p[2][4][4];
#pragma unroll
      for (int qp = 0; qp < 2; ++qp) {
        float mk[4];
#pragma unroll
        for (int kt = 0; kt < 4; ++kt)
          mk[kt] = fmaxf(fmaxf(s[qp * 4 + kt][0], s[qp * 4 + kt][1]),
                         fmaxf(s[qp * 4 + kt][2], s[qp * 4 + kt][3]));
        float mx = fmaxf(fmaxf(mk[0], mk[1]), fmaxf(mk[2], mk[3]));
        mx = fmaxf(mx, __shfl_xor(mx, 16));
        mx = fmaxf(mx, __shfl_xor(mx, 32));
        float mnew = fmaxf(mrow[qp], mx);
        float msc = mnew * sc2;
        float corr = fast_exp2(__builtin_fmaf(mrow[qp], sc2, -msc));
        mrow[qp] = mnew;
        float sk[4];
#pragma unroll
        for (int kt = 0; kt < 4; ++kt) {
#pragma unroll
          for (int r = 0; r < 4; ++r)
            p[qp][kt][r] = fast_exp2(__builtin_fmaf(s[qp * 4 + kt][r], sc2, -msc));
          sk[kt] = (p[qp][kt][0] + p[qp][kt][1]) + (p[qp][kt][2] + p[qp][kt][3]);
        }
        float rs = (sk[0] + sk[1]) + (sk[2] + sk[3]);
        rs += __shfl_xor(rs, 16);
        rs += __shfl_xor(rs, 32);
        lrow[qp] = lrow[qp] * corr + rs;
#pragma unroll
        for (int dt = 0; dt < 4; ++dt) Oacc[qp * 4 + dt] *= corr;
      }
      // ---- pack P to bf16 B-frags in-register (slot order = MODE 3 perm) ----
      short8v fbv[4];   // [q'*2 + sl]
#pragma unroll
      for (int qp = 0; qp < 2; ++qp)
#pragma unroll
        for (int sl = 0; sl < 2; ++sl) {
          union { u32 u[4]; short8v v; } fq;
          fq.u[0] = cvt_pk_bf16(p[qp][2 * sl][0], p[qp][2 * sl][1]);
          fq.u[1] = cvt_pk_bf16(p[qp][2 * sl][2], p[qp][2 * sl][3]);
          fq.u[2] = cvt_pk_bf16(p[qp][2 * sl + 1][0], p[qp][2 * sl + 1][1]);
          fq.u[3] = cvt_pk_bf16(p[qp][2 * sl + 1][2], p[qp][2 * sl + 1][3]);
          fbv[qp * 2 + sl] = fq.v;
        }
      // ---- PV swapped: 8 ds_read feed 16 MFMA ----
      __builtin_amdgcn_s_setprio(1);
#pragma unroll
      for (int dt = 0; dt < 4; ++dt) {
        int d = dt * 16 + (l & 15);
#pragma unroll
        for (int sl = 0; sl < 2; ++sl) {
          int kstart = ((l >> 4) * 8 + 32 * sl) ^ ((d & 7) << 3);
          short8v fav = *(const short8v*)&Vt_s[d * 64 + kstart];
#pragma unroll
          for (int qp = 0; qp < 2; ++qp)
            Oacc[qp * 4 + dt] = __builtin_amdgcn_mfma_f32_16x16x32_bf16(fav, fbv[qp * 2 + sl], Oacc[qp * 4 + dt], 0, 0, 0);
        }
      }
      __builtin_amdgcn_s_setprio(0);
    }
    __syncthreads();             // single barrier: writes visible, reads done
  }
  // ---- epilogue: transpose Oacc via LDS scratch, coalesced AO store ----
  float* Es = (float*)SM + w * (16 * 68);
#pragma unroll
  for (int qp = 0; qp < 2; ++qp) {
    float invl = 1.0f / lrow[qp];
#pragma unroll
    for (int dt = 0; dt < 4; ++dt)
#pragma unroll
      for (int r = 0; r < 4; ++r)
        Es[(l & 15) * 68 + dt * 16 + ((l >> 4) << 2) + r] = Oacc[qp * 4 + dt][r] * invl;
    size_t arow = ((size_t)(b * Tc + q0 + w * 32 + qp * 16 + (l >> 2))) * Dc + h * 64 + (l & 3) * 4;
#pragma unroll
    for (int j = 0; j < 4; ++j) {
      float4 vv = *(const float4*)&Es[(l >> 2) * 68 + (l & 3) * 4 + j * 16];
      *(float4*)&AO[arow + j * 16] = vv;
    }
  }
#undef AISSUE3
#undef WRITEBUF
}

// ---------------- launch ----------------
extern "C" void kernel_launch(void* const* d_in, const int* in_sizes, int n_in,
                              void* d_out, int out_size, void* d_ws, size_t ws_size,
                              hipStream_t stream) {
  const float* x    = (const float*)d_in[0];
  const float* q_w  = (const float*)d_in[1];
  const float* q_g  = (const float*)d_in[2];
  const float* k_w  = (const float*)d_in[3];
  const float* k_g  = (const float*)d_in[4];
  const float* v_w  = (const float*)d_in[5];
  const float* o_w  = (const float*)d_in[6];
  const float* o_g  = (const float*)d_in[7];
  const float* qk_g = (const float*)d_in[8];

  // workspace (bytes), peak ~61.2 MB
  char* base = (char*)d_ws;
  u16* Xqh = (u16*)(base + (0ull  << 20));   // 8MB
  u16* Xql = (u16*)(base + (8ull  << 20));   // 8MB
  u16* Xkh = (u16*)(base + (16ull << 20));   // 8MB
  u16* Xkl = (u16*)(base + (24ull << 20));   // 8MB
  u16* Xvh = (u16*)(base + (32ull << 20));   // 8MB
  u16* Xvl = (u16*)(base + (40ull << 20));   // 8MB (Ql overlay region only)
  u16* Kh  = (u16*)(base + (48ull << 20));   // 2MB
  u16* Kl  = (u16*)(base + (50ull << 20));   // 2MB
  u16* Vt  = (u16*)(base + (52ull << 20));   // 2MB  [256][4096], slot-permuted per 32
  u16* Wq  = (u16*)(base + (54ull << 20));   // 2MB
  u16* Wk  = (u16*)(base + (56ull << 20));   // 0.5MB
  u16* Wo  = (u16*)(base + (57ull << 20));   // 2MB
  u16* Vwh = (u16*)(base + (59ull << 20));   // 0.5MB
  float* leaf = (float*)(base + (61ull << 20)); // 18432 floats (Q 8192 | K 2048 | O 8192)
  float* th   = leaf + 18432;                // 3
  // overlays
  float* AO  = (float*)base;                 // 16MB over Xqh/Xql (dead after Q-proj)
  u16* Xoh = Xkh;                            // over Xk (dead after K-proj)
  u16* Qh  = Xvh; u16* Ql  = Xvl;            // over Xv region (Xvh dead after V-proj)

  // 1) numpy-exact fp32 thresholds
  np_leafsum_all<<<576, 256, 0, stream>>>(q_w, k_w, o_w, leaf);
  np_treemean3<<<3, 256, 0, stream>>>(leaf, th);

  // 2) quantize ternary weights -> bf16 + v_w bf16 cast (one launch)
  quant_split_all<<<2560, 256, 0, stream>>>(q_w, k_w, o_w, v_w, th, Wq, Wk, Wo, Vwh);

  // 3) RMSNorm(x) -> bf16 hi/lo (q,k gains) + raw-x bf16 (V path)
  rmsnorm_split6<<<Mc, 256, 0, stream>>>(x, q_g, k_g, Xqh, Xql, Xkh, Xkl, Xvh);

  // 4) projections (MFMA). V first (Q output overlays Xv).
  //    V: Vt[256][4096] = Vw @ x^T, SINGLE-pass bf16, slot-permuted cols. 64x64 tiles.
  gemm_mfma<false, false, 3, 2, 2><<<dim3(64, 4), 256, 0, stream>>>(
      Vwh, nullptr, Xvh, nullptr, 256, Mc, 1024, nullptr, Vt, nullptr);
  //    Q: 2-pass (A hi/lo), hi/lo bf16 out, 64x128 tiles.
  gemm_mfma<true, false, 1, 2, 4><<<dim3(8, 64), 256, 0, stream>>>(
      Xqh, Xql, Wq, nullptr, Mc, 1024, 1024, nullptr, Qh, Ql);
  //    K: 2-pass (A hi/lo), hi/lo bf16 out, 64x64 tiles.
  gemm_mfma<true, false, 1, 2, 2><<<dim3(4, 64), 256, 0, stream>>>(
      Xkh, Xkl, Wk, nullptr, Mc, 256, 1024, nullptr, Kh, Kl);

  // 5) MFMA causal GQA attention v9 -> AO fp32
  attn_mfma9<<<dim3(32, 16, 1), 256, 0, stream>>>(Qh, Ql, Kh, Kl, Vt, qk_g, AO);

  // 6) output bitlinear: single-pass bf16 A
  rmsnorm_split6<<<Mc, 256, 0, stream>>>(AO, o_g, nullptr, Xoh, nullptr, nullptr, nullptr,
                                         nullptr);
  gemm_mfma<false, false, 0, 2, 4><<<dim3(8, 64), 256, 0, stream>>>(
      Xoh, nullptr, Wo, nullptr, Mc, 1024, 1024, (float*)d_out, nullptr, nullptr);
}

// Round 16
// 138.656 us; speedup vs baseline: 2.2198x; 1.0796x over previous
//
#include <hip/hip_runtime.h>
#include <hip/hip_bf16.h>
#include <cstdint>
#include <cstddef>

typedef unsigned short u16;
typedef unsigned int u32;
typedef __attribute__((ext_vector_type(8))) short short8v;   // 8 bf16 MFMA frag
typedef __attribute__((ext_vector_type(4))) float f32x4;     // MFMA accumulator
typedef __attribute__((ext_vector_type(4))) u16 u16x4;
typedef __attribute__((ext_vector_type(8))) u16 u16x8;

// Problem constants
static constexpr int Bc = 2, Tc = 2048, Dc = 1024, Hc = 16, HKVc = 4, HDc = 64;
static constexpr int Mc = Bc * Tc;                 // 4096 rows
static constexpr float EPSc = 1.1920929e-07f;

static __device__ __forceinline__ u16 f2bf(float f) {
  u32 u = __builtin_bit_cast(u32, f);
  return (u16)((u + 0x7fffu + ((u >> 16) & 1u)) >> 16);
}
static __device__ __forceinline__ float bf2f(u16 b) {
  u32 u = ((u32)b) << 16;
  return __builtin_bit_cast(float, u);
}
static __device__ __forceinline__ float fast_exp2(float x) {
  float r;
  asm("v_exp_f32 %0, %1" : "=v"(r) : "v"(x));
  return r;
}
static __device__ __forceinline__ u32 cvt_pk_bf16(float lo, float hi) {
  u32 r;
  asm("v_cvt_pk_bf16_f32 %0, %1, %2" : "=v"(r) : "v"(lo), "v"(hi));
  return r;
}

// ---------------- numpy-exact fp32 pairwise abs-mean (verified round 3/7) ----------------
__global__ __launch_bounds__(256) void np_leafsum_all(const float* __restrict__ q_w,
                                                      const float* __restrict__ k_w,
                                                      const float* __restrict__ o_w,
                                                      float* __restrict__ leaf) {
  int blk = blockIdx.x;
  const float* w;
  float* out;
  int lfbase;
  if (blk < 256)      { w = q_w; out = leaf;         lfbase = blk * 32; }
  else if (blk < 320) { w = k_w; out = leaf + 8192;  lfbase = (blk - 256) * 32; }
  else                { w = o_w; out = leaf + 10240; lfbase = (blk - 320) * 32; }
  int t = threadIdx.x;
  int lf = lfbase + (t >> 3), j = t & 7;
  const float* a = w + (size_t)lf * 128;
  float r = fabsf(a[j]);
#pragma unroll
  for (int i = 8; i < 128; i += 8) r += fabsf(a[i + j]);
  float x = r + __shfl_xor(r, 1);
  float y = x + __shfl_xor(x, 2);
  float z = y + __shfl_xor(y, 4);
  if (j == 0) out[lf] = z;
}

__global__ __launch_bounds__(256) void np_treemean3(const float* __restrict__ leaf,
                                                    float* __restrict__ th) {
  int m = blockIdx.x;
  const float* src = leaf + (m == 0 ? 0 : (m == 1 ? 8192 : 10240));
  int nle = (m == 1) ? 2048 : 8192;
  float inv_n = (m == 1) ? (1.0f / 262144.0f) : (1.0f / 1048576.0f);
  int t = threadIdx.x;
  int chunk = nle >> 8;                      // 32 or 8, power of two
  float v[32];
  for (int i = 0; i < chunk; i += 4) {
    float4 f = *(const float4*)&src[t * chunk + i];
    v[i] = f.x; v[i + 1] = f.y; v[i + 2] = f.z; v[i + 3] = f.w;
  }
  for (int cnt = chunk >> 1; cnt >= 1; cnt >>= 1)
    for (int i = 0; i < cnt; ++i) v[i] = v[2 * i] + v[2 * i + 1];
  float s = v[0];
#pragma unroll
  for (int off = 1; off < 64; off <<= 1) s += __shfl_xor(s, off);
  __shared__ float red[4];
  if ((t & 63) == 0) red[t >> 6] = s;
  __syncthreads();
  if (t == 0) th[m] = ((red[0] + red[1]) + (red[2] + red[3])) * inv_n;
}

// ---------------- fused: ternary quantize (q/k/o) + v_w bf16 cast ----------------
__global__ __launch_bounds__(256) void quant_split_all(const float* __restrict__ q_w,
                                                       const float* __restrict__ k_w,
                                                       const float* __restrict__ o_w,
                                                       const float* __restrict__ v_w,
                                                       const float* __restrict__ th,
                                                       u16* __restrict__ Wq,
                                                       u16* __restrict__ Wk,
                                                       u16* __restrict__ Wo,
                                                       u16* __restrict__ Vwh) {
  int i4 = blockIdx.x * 256 + threadIdx.x;   // float4 index
  if (i4 < 589824) {
    const float* w; u16* o; float t;
    int j;
    if (i4 < 262144)      { w = q_w; o = Wq; t = th[0]; j = i4; }
    else if (i4 < 327680) { w = k_w; o = Wk; t = th[1]; j = i4 - 262144; }
    else                  { w = o_w; o = Wo; t = th[2]; j = i4 - 327680; }
    float4 v = *(const float4*)&w[(size_t)j * 4];
    float y[4] = {v.x, v.y, v.z, v.w};
    u16x4 q;
#pragma unroll
    for (int c = 0; c < 4; ++c)
      q[c] = (y[c] > t) ? (u16)0x3F80 : ((y[c] < -t) ? (u16)0xBF80 : (u16)0);
    *(u16x4*)&o[(size_t)j * 4] = q;
  } else {
    int j = i4 - 589824;                     // v_w float4 index, [0, 65536)
    float4 v = *(const float4*)&v_w[(size_t)j * 4];
    float y[4] = {v.x, v.y, v.z, v.w};
    u16x4 h;
#pragma unroll
    for (int c = 0; c < 4; ++c) h[c] = f2bf(y[c]);
    *(u16x4*)&Vwh[(size_t)j * 4] = h;
  }
}

// ---------------- RMSNorm -> bf16 (hi or hi/lo) x2 gains + raw-x bf16 ----------------
__global__ __launch_bounds__(256) void rmsnorm_split6(const float* __restrict__ X,
                                                      const float* __restrict__ g1,
                                                      const float* __restrict__ g2,
                                                      u16* __restrict__ H1, u16* __restrict__ L1,
                                                      u16* __restrict__ H2, u16* __restrict__ L2,
                                                      u16* __restrict__ HV) {
  int row = blockIdx.x;
  const float* xr = X + (size_t)row * Dc;
  int tid = threadIdx.x;
  float4 v = *(const float4*)&xr[tid * 4];
  float vv[4] = {v.x, v.y, v.z, v.w};
  if (HV != nullptr) {           // raw x bf16 for the single-pass V path
    u16x4 h;
#pragma unroll
    for (int j = 0; j < 4; ++j) h[j] = f2bf(vv[j]);
    *(u16x4*)&HV[(size_t)row * Dc + tid * 4] = h;
  }
  float ss = v.x * v.x + v.y * v.y + v.z * v.z + v.w * v.w;
#pragma unroll
  for (int off = 1; off < 64; off <<= 1) ss += __shfl_xor(ss, off);
  __shared__ float red[4];
  if ((tid & 63) == 0) red[tid >> 6] = ss;
  __syncthreads();
  float tot = red[0] + red[1] + red[2] + red[3];
  float inv = 1.0f / sqrtf(tot * (1.0f / (float)Dc) + EPSc);
  {
    float4 a = *(const float4*)&g1[tid * 4];
    float ga[4] = {a.x, a.y, a.z, a.w};
    u16x4 h, l;
#pragma unroll
    for (int j = 0; j < 4; ++j) {
      float y = vv[j] * inv * ga[j];
      u16 hb = f2bf(y);
      h[j] = hb;
      l[j] = f2bf(y - bf2f(hb));
    }
    *(u16x4*)&H1[(size_t)row * Dc + tid * 4] = h;
    if (L1 != nullptr) *(u16x4*)&L1[(size_t)row * Dc + tid * 4] = l;
  }
  if (g2 != nullptr) {
    float4 a = *(const float4*)&g2[tid * 4];
    float ga[4] = {a.x, a.y, a.z, a.w};
    u16x4 h, l;
#pragma unroll
    for (int j = 0; j < 4; ++j) {
      float y = vv[j] * inv * ga[j];
      u16 hb = f2bf(y);
      h[j] = hb;
      l[j] = f2bf(y - bf2f(hb));
    }
    *(u16x4*)&H2[(size_t)row * Dc + tid * 4] = h;
    if (L2 != nullptr) *(u16x4*)&L2[(size_t)row * Dc + tid * 4] = l;
  }
}

// ---------------- shared GEMM body: 64x128 tile, BK=64, 4 waves (2x2), optional A-lo pass ----------------
// MODE 0: C fp32.  MODE 1: O1/O2 = bf16 hi/lo.  MODE 3: O1 = bf16, cols permuted
// within each 32-block by gp(k) = (k&~31) | ((k>>2)&3)<<3 | ((k>>4)&1)<<2 | (k&3)
// (matches attn's in-register P slot order for the swapped-PV MFMA; verified r9-r14).
// LDS layout in smem (u16): AhS [0,4096) | AlS [4096,8192) | BhS [8192,16384)  (32KB)
template <bool PA, int MODE>
static __device__ __forceinline__ void gemm_body(
    const u16* __restrict__ Ah, const u16* __restrict__ Al,
    const u16* __restrict__ Bh,
    int N, int K, int bm, int bn,
    float* __restrict__ C, u16* __restrict__ O1, u16* __restrict__ O2,
    u16* smem) {
  constexpr int APT = 2, BPT = 4;
  u16* AhS = smem;
  u16* AlS = smem + 4096;
  u16* BhS = smem + 8192;
  int tid = threadIdx.x;
  int l = tid & 63, w = tid >> 6;
  int wm = (w >> 1) * 32, wn = (w & 1) * 64;
  u16x8 rAh[APT], rAl[PA ? APT : 1], rBh[BPT];
  f32x4 acc[2][4] = {};
#define LOADTILE(kb_)                                                               \
  {                                                                                 \
    _Pragma("unroll") for (int p = 0; p < APT; ++p) {                               \
      int idx = tid + p * 256;                                                      \
      int row = idx >> 3, cc = idx & 7;                                             \
      rAh[p] = *(const u16x8*)&Ah[(size_t)(bm + row) * K + (kb_) + cc * 8];         \
      if (PA) rAl[p] = *(const u16x8*)&Al[(size_t)(bm + row) * K + (kb_) + cc * 8]; \
    }                                                                               \
    _Pragma("unroll") for (int p = 0; p < BPT; ++p) {                               \
      int idx = tid + p * 256;                                                      \
      int row = idx >> 3, cc = idx & 7;                                             \
      rBh[p] = *(const u16x8*)&Bh[(size_t)(bn + row) * K + (kb_) + cc * 8];         \
    }                                                                               \
  }
  LOADTILE(0)
  for (int kb = 0; kb < K; kb += 64) {
    __syncthreads();
#pragma unroll
    for (int p = 0; p < APT; ++p) {
      int idx = tid + p * 256;
      int row = idx >> 3, cc = idx & 7;
      int off = row * 64 + ((cc * 8) ^ ((row & 7) << 3));
      *(u16x8*)&AhS[off] = rAh[p];
      if (PA) *(u16x8*)&AlS[off] = rAl[p];
    }
#pragma unroll
    for (int p = 0; p < BPT; ++p) {
      int idx = tid + p * 256;
      int row = idx >> 3, cc = idx & 7;
      int off = row * 64 + ((cc * 8) ^ ((row & 7) << 3));
      *(u16x8*)&BhS[off] = rBh[p];
    }
    if (kb + 64 < K) LOADTILE(kb + 64)
    __syncthreads();
    __builtin_amdgcn_s_setprio(1);
#pragma unroll
    for (int sl = 0; sl < 2; ++sl) {
      short8v fa[2], fal[2], fb[4];
      int kof = (l >> 4) * 8 + sl * 32;
#pragma unroll
      for (int m = 0; m < 2; ++m) {
        int row = wm + m * 16 + (l & 15);
        int off = row * 64 + (kof ^ ((row & 7) << 3));
        fa[m] = *(const short8v*)&AhS[off];
        if (PA) fal[m] = *(const short8v*)&AlS[off];
      }
#pragma unroll
      for (int n = 0; n < 4; ++n) {
        int row = wn + n * 16 + (l & 15);
        int off = row * 64 + (kof ^ ((row & 7) << 3));
        fb[n] = *(const short8v*)&BhS[off];
      }
#pragma unroll
      for (int m = 0; m < 2; ++m)
#pragma unroll
        for (int n = 0; n < 4; ++n) {
          acc[m][n] = __builtin_amdgcn_mfma_f32_16x16x32_bf16(fa[m], fb[n], acc[m][n], 0, 0, 0);
          if (PA)
            acc[m][n] = __builtin_amdgcn_mfma_f32_16x16x32_bf16(fal[m], fb[n], acc[m][n], 0, 0, 0);
        }
    }
    __builtin_amdgcn_s_setprio(0);
  }
#undef LOADTILE
#pragma unroll
  for (int m = 0; m < 2; ++m)
#pragma unroll
    for (int n = 0; n < 4; ++n)
#pragma unroll
      for (int r = 0; r < 4; ++r) {
        int grow = bm + wm + m * 16 + (l >> 4) * 4 + r;
        int gcol = bn + wn + n * 16 + (l & 15);
        float v = acc[m][n][r];
        if (MODE == 0) {
          C[(size_t)grow * N + gcol] = v;
        } else if (MODE == 1) {
          u16 hb = f2bf(v);
          O1[(size_t)grow * N + gcol] = hb;
          O2[(size_t)grow * N + gcol] = f2bf(v - bf2f(hb));
        } else {
          int k = gcol & 31;
          int gp = (gcol & ~31) | (((k >> 2) & 3) << 3) |
                   (((k >> 4) & 1) << 2) | (k & 3);
          O1[(size_t)grow * N + gp] = f2bf(v);
        }
      }
}

// ---------------- fused QKV projections: one launch, 768 blocks ----------------
// [0,512): Q (2-pass, hi/lo out).  [512,640): K (2-pass, hi/lo out).
// [640,768): V (1-pass, Vt slot-permuted out).  All 64x128 tiles, 32KB LDS.
// NOTE: Qh/Ql/Kh/Kl/Vt are DEDICATED regions (no overlay with inputs) — r15's race fix.
__global__ __launch_bounds__(256, 1) void qkv_mega(
    const u16* __restrict__ Xqh, const u16* __restrict__ Xql, const u16* __restrict__ Wq,
    const u16* __restrict__ Xkh, const u16* __restrict__ Xkl, const u16* __restrict__ Wk,
    const u16* __restrict__ Xvh, const u16* __restrict__ Vwh,
    u16* __restrict__ Qh, u16* __restrict__ Ql,
    u16* __restrict__ Kh, u16* __restrict__ Kl,
    u16* __restrict__ Vt) {
  __shared__ __align__(16) u16 SMEM[16384];   // 32KB
  int bx = blockIdx.x;
  if (bx < 512) {
    // Q: C[4096,1024] = Xq(hi/lo) @ Wq^T
    int bm = (bx >> 3) * 64, bn = (bx & 7) * 128;
    gemm_body<true, 1>(Xqh, Xql, Wq, 1024, 1024, bm, bn, nullptr, Qh, Ql, SMEM);
  } else if (bx < 640) {
    // K: C[4096,256] = Xk(hi/lo) @ Wk^T
    int t = bx - 512;
    int bm = (t >> 1) * 64, bn = (t & 1) * 128;
    gemm_body<true, 1>(Xkh, Xkl, Wk, 256, 1024, bm, bn, nullptr, Kh, Kl, SMEM);
  } else {
    // V: Vt[256,4096] = Vw @ x^T (1-pass), slot-permuted cols
    int t = bx - 640;
    int bm = (t >> 5) * 64, bn = (t & 31) * 128;
    gemm_body<false, 3>(Vwh, nullptr, Xvh, 4096, 1024, bm, bn, nullptr, Vt, nullptr, SMEM);
  }
}

// ---------------- O-projection GEMM (MODE 0, 1-pass) ----------------
__global__ __launch_bounds__(256, 1) void o_gemm(
    const u16* __restrict__ Ah, const u16* __restrict__ Bh,
    float* __restrict__ C) {
  __shared__ __align__(16) u16 SMEM[16384];
  int bm = blockIdx.y * 64, bn = blockIdx.x * 128;
  gemm_body<false, 0>(Ah, nullptr, Bh, 1024, 1024, bm, bn, C, nullptr, nullptr, SMEM);
}

// ---------------- MFMA causal GQA attention v9 (unchanged from r14, verified) ----------------
__global__ __launch_bounds__(256, 2) void attn_mfma9(
    const u16* __restrict__ Qh, const u16* __restrict__ Ql,
    const u16* __restrict__ Kh, const u16* __restrict__ Kl,
    const u16* __restrict__ Vt,
    const float* __restrict__ qk_gain,
    float* __restrict__ AO) {
  __shared__ __align__(16) u16 SM[24576];   // 2 x (Kh 4096 | Kl 4096 | Vt 4096) u16 = 48KB
  int tid = threadIdx.x;
  int w = tid >> 6, l = tid & 63;
  int h = blockIdx.x & 15, b = blockIdx.x >> 4;
  int by = blockIdx.y;
  int qt = (by < 8) ? (15 - by) : (by - 8);   // largest tiles dispatch first
  int q0 = qt * 128;
  int kvh = h >> 2;
  const float sc2 = qk_gain[0] * 0.125f * 1.44269504f;   // v_exp_f32 computes 2^x
  u16x8 pk[2], pl[2], pv[2];
#define AISSUE3(K0)                                                             \
  {                                                                             \
    _Pragma("unroll") for (int p = 0; p < 2; ++p) {                             \
      int idx = tid + p * 256;                                                  \
      int jj = idx >> 3, cc = idx & 7;                                          \
      size_t kb = ((size_t)(b * Tc + (K0) + jj)) * (HKVc * HDc) + kvh * 64 + cc * 8; \
      pk[p] = *(const u16x8*)&Kh[kb];                                           \
      pl[p] = *(const u16x8*)&Kl[kb];                                           \
      size_t vb = ((size_t)(kvh * 64 + jj)) * (size_t)Mc + b * Tc + (K0) + cc * 8; \
      pv[p] = *(const u16x8*)&Vt[vb];                                           \
    }                                                                           \
  }
#define WRITEBUF(BI)                                                            \
  {                                                                             \
    u16* bb = SM + (BI) * 12288;                                                \
    _Pragma("unroll") for (int p = 0; p < 2; ++p) {                             \
      int idx = tid + p * 256;                                                  \
      int jj = idx >> 3, cc = idx & 7;                                          \
      int sw = jj * 64 + ((cc * 8) ^ ((jj & 7) << 3));                          \
      *(u16x8*)&bb[sw] = pk[p];                                                 \
      *(u16x8*)&bb[4096 + sw] = pl[p];                                          \
      *(u16x8*)&bb[8192 + sw] = pv[p];                                          \
    }                                                                           \
  }
  // Q B-frags straight from global: wave covers q-cols [w*32, w*32+32), 2 frags of 16
  short8v qb_h[4], qb_l[4];   // [q'*2 + sl]
#pragma unroll
  for (int qp = 0; qp < 2; ++qp) {
    size_t qrow = (size_t)(b * Tc + q0 + w * 32 + qp * 16 + (l & 15));
#pragma unroll
    for (int sl = 0; sl < 2; ++sl) {
      int dstart = (l >> 4) * 8 + sl * 32;
      qb_h[qp * 2 + sl] = *(const short8v*)&Qh[qrow * Dc + h * 64 + dstart];
      qb_l[qp * 2 + sl] = *(const short8v*)&Ql[qrow * Dc + h * 64 + dstart];
    }
  }
  f32x4 Oacc[8] = {{0,0,0,0},{0,0,0,0},{0,0,0,0},{0,0,0,0},
                   {0,0,0,0},{0,0,0,0},{0,0,0,0},{0,0,0,0}};   // [q'*4 + dt]
  float mrow[2] = {-3.0e38f, -3.0e38f};
  float lrow[2] = {0.f, 0.f};
  int qmax_w = q0 + w * 32 + 31;
  int nsteps = 2 * qt + 2;
  // ---- prologue: tile0 -> buf0, tile1 -> regs ----
  AISSUE3(0)
  WRITEBUF(0)
  AISSUE3(64)
  __syncthreads();               // buf0 visible
  for (int stp = 0; stp < nsteps; ++stp) {
    int k0 = stp * 64;
    u16* Kh_s = SM + (stp & 1) * 12288;
    u16* Kl_s = Kh_s + 4096;
    u16* Vt_s = Kh_s + 8192;
    // pipeline: write tile s+1 to the other buffer; issue loads for tile s+2
    if (stp + 1 < nsteps) WRITEBUF((stp + 1) & 1)
    if (stp + 2 < nsteps) AISSUE3((stp + 2) * 64)
    if (k0 <= qmax_w) {
      // ---- QK^T swapped: s = K_tile x Q -> S[key][q]; 16 ds_read feed 48 MFMA ----
      f32x4 s[8] = {{0,0,0,0},{0,0,0,0},{0,0,0,0},{0,0,0,0},
                    {0,0,0,0},{0,0,0,0},{0,0,0,0},{0,0,0,0}};   // [q'*4 + kt]
      __builtin_amdgcn_s_setprio(1);
#pragma unroll
      for (int kt = 0; kt < 4; ++kt) {
        int key = kt * 16 + (l & 15);
#pragma unroll
        for (int sl = 0; sl < 2; ++sl) {
          int dstart = ((l >> 4) * 8 + 32 * sl) ^ ((key & 7) << 3);
          short8v bh = *(const short8v*)&Kh_s[key * 64 + dstart];
          short8v bl = *(const short8v*)&Kl_s[key * 64 + dstart];
#pragma unroll
          for (int qp = 0; qp < 2; ++qp) {
            s[qp * 4 + kt] = __builtin_amdgcn_mfma_f32_16x16x32_bf16(bh, qb_h[qp * 2 + sl], s[qp * 4 + kt], 0, 0, 0);
            s[qp * 4 + kt] = __builtin_amdgcn_mfma_f32_16x16x32_bf16(bl, qb_h[qp * 2 + sl], s[qp * 4 + kt], 0, 0, 0);
            s[qp * 4 + kt] = __builtin_amdgcn_mfma_f32_16x16x32_bf16(bh, qb_l[qp * 2 + sl], s[qp * 4 + kt], 0, 0, 0);
          }
        }
      }
      __builtin_amdgcn_s_setprio(0);
      // ---- causal mask (lane-local; wave-uniform fast path) ----
      bool full = (k0 + 63) <= (q0 + w * 32);
      if (!full) {
#pragma unroll
        for (int qp = 0; qp < 2; ++qp) {
          int qg = q0 + w * 32 + qp * 16 + (l & 15);
#pragma unroll
          for (int kt = 0; kt < 4; ++kt)
#pragma unroll
            for (int r = 0; r < 4; ++r)
              if (k0 + kt * 16 + ((l >> 4) << 2) + r > qg) s[qp * 4 + kt][r] = -3.0e38f;
        }
      }
      // ---- softmax per q'-group: 15 local fmax + 2 shfl ----
      float p[2][4][4];
#pragma unroll
      for (int qp = 0; qp < 2; ++qp) {
        float mk[4];
#pragma unroll
        for (int kt = 0; kt < 4; ++kt)
          mk[kt] = fmaxf(fmaxf(s[qp * 4 + kt][0], s[qp * 4 + kt][1]),
                         fmaxf(s[qp * 4 + kt][2], s[qp * 4 + kt][3]));
        float mx = fmaxf(fmaxf(mk[0], mk[1]), fmaxf(mk[2], mk[3]));
        mx = fmaxf(mx, __shfl_xor(mx, 16));
        mx = fmaxf(mx, __shfl_xor(mx, 32));
        float mnew = fmaxf(mrow[qp], mx);
        float msc = mnew * sc2;
        float corr = fast_exp2(__builtin_fmaf(mrow[qp], sc2, -msc));
        mrow[qp] = mnew;
        float sk[4];
#pragma unroll
        for (int kt = 0; kt < 4; ++kt) {
#pragma unroll
          for (int r = 0; r < 4; ++r)
            p[qp][kt][r] = fast_exp2(__builtin_fmaf(s[qp * 4 + kt][r], sc2, -msc));
          sk[kt] = (p[qp][kt][0] + p[qp][kt][1]) + (p[qp][kt][2] + p[qp][kt][3]);
        }
        float rs = (sk[0] + sk[1]) + (sk[2] + sk[3]);
        rs += __shfl_xor(rs, 16);
        rs += __shfl_xor(rs, 32);
        lrow[qp] = lrow[qp] * corr + rs;
#pragma unroll
        for (int dt = 0; dt < 4; ++dt) Oacc[qp * 4 + dt] *= corr;
      }
      // ---- pack P to bf16 B-frags in-register (slot order = MODE 3 perm) ----
      short8v fbv[4];   // [q'*2 + sl]
#pragma unroll
      for (int qp = 0; qp < 2; ++qp)
#pragma unroll
        for (int sl = 0; sl < 2; ++sl) {
          union { u32 u[4]; short8v v; } fq;
          fq.u[0] = cvt_pk_bf16(p[qp][2 * sl][0], p[qp][2 * sl][1]);
          fq.u[1] = cvt_pk_bf16(p[qp][2 * sl][2], p[qp][2 * sl][3]);
          fq.u[2] = cvt_pk_bf16(p[qp][2 * sl + 1][0], p[qp][2 * sl + 1][1]);
          fq.u[3] = cvt_pk_bf16(p[qp][2 * sl + 1][2], p[qp][2 * sl + 1][3]);
          fbv[qp * 2 + sl] = fq.v;
        }
      // ---- PV swapped: 8 ds_read feed 16 MFMA ----
      __builtin_amdgcn_s_setprio(1);
#pragma unroll
      for (int dt = 0; dt < 4; ++dt) {
        int d = dt * 16 + (l & 15);
#pragma unroll
        for (int sl = 0; sl < 2; ++sl) {
          int kstart = ((l >> 4) * 8 + 32 * sl) ^ ((d & 7) << 3);
          short8v fav = *(const short8v*)&Vt_s[d * 64 + kstart];
#pragma unroll
          for (int qp = 0; qp < 2; ++qp)
            Oacc[qp * 4 + dt] = __builtin_amdgcn_mfma_f32_16x16x32_bf16(fav, fbv[qp * 2 + sl], Oacc[qp * 4 + dt], 0, 0, 0);
        }
      }
      __builtin_amdgcn_s_setprio(0);
    }
    __syncthreads();             // single barrier: writes visible, reads done
  }
  // ---- epilogue: transpose Oacc via LDS scratch, coalesced AO store ----
  float* Es = (float*)SM + w * (16 * 68);
#pragma unroll
  for (int qp = 0; qp < 2; ++qp) {
    float invl = 1.0f / lrow[qp];
#pragma unroll
    for (int dt = 0; dt < 4; ++dt)
#pragma unroll
      for (int r = 0; r < 4; ++r)
        Es[(l & 15) * 68 + dt * 16 + ((l >> 4) << 2) + r] = Oacc[qp * 4 + dt][r] * invl;
    size_t arow = ((size_t)(b * Tc + q0 + w * 32 + qp * 16 + (l >> 2))) * Dc + h * 64 + (l & 3) * 4;
#pragma unroll
    for (int j = 0; j < 4; ++j) {
      float4 vv = *(const float4*)&Es[(l >> 2) * 68 + (l & 3) * 4 + j * 16];
      *(float4*)&AO[arow + j * 16] = vv;
    }
  }
#undef AISSUE3
#undef WRITEBUF
}

// ---------------- launch ----------------
extern "C" void kernel_launch(void* const* d_in, const int* in_sizes, int n_in,
                              void* d_out, int out_size, void* d_ws, size_t ws_size,
                              hipStream_t stream) {
  const float* x    = (const float*)d_in[0];
  const float* q_w  = (const float*)d_in[1];
  const float* q_g  = (const float*)d_in[2];
  const float* k_w  = (const float*)d_in[3];
  const float* k_g  = (const float*)d_in[4];
  const float* v_w  = (const float*)d_in[5];
  const float* o_w  = (const float*)d_in[6];
  const float* o_g  = (const float*)d_in[7];
  const float* qk_g = (const float*)d_in[8];

  // workspace (bytes), peak ~67.1 MB — Qh/Ql now DEDICATED (no overlay with qkv_mega
  // inputs; r15's Qh=Xvh overlay raced against concurrent V-proj reads).
  char* base = (char*)d_ws;
  u16* Xqh = (u16*)(base + (0ull  << 20));       // 8MB  [dead after qkv_mega]
  u16* Xql = (u16*)(base + (8ull  << 20));       // 8MB  [dead after qkv_mega]
  u16* Xkh = (u16*)(base + (16ull << 20));       // 8MB  [dead after qkv_mega]
  u16* Xkl = (u16*)(base + (24ull << 20));       // 8MB  [dead after qkv_mega]
  u16* Xvh = (u16*)(base + (32ull << 20));       // 8MB  [dead after qkv_mega]
  u16* Qh  = (u16*)(base + (40ull << 20));       // 8MB  dedicated
  u16* Ql  = (u16*)(base + (48ull << 20));       // 8MB  dedicated
  u16* Kh  = (u16*)(base + (56ull << 20));       // 2MB
  u16* Kl  = (u16*)(base + (58ull << 20));       // 2MB
  u16* Vt  = (u16*)(base + (60ull << 20));       // 2MB  [256][4096], slot-permuted per 32
  u16* Wq  = (u16*)(base + (62ull << 20));       // 2MB
  u16* Wk  = (u16*)(base + (64ull << 20));       // 0.5MB
  u16* Wo  = (u16*)(base + (64ull << 20) + (512ull << 10));   // 2MB
  u16* Vwh = (u16*)(base + (66ull << 20) + (512ull << 10));   // 0.5MB
  float* leaf = (float*)(base + (67ull << 20));  // 18432 floats (Q 8192 | K 2048 | O 8192)
  float* th   = leaf + 18432;                    // 3
  // overlays (sequential-launch safe: regions dead before writer launches)
  float* AO  = (float*)base;                     // 16MB over Xqh/Xql (dead after qkv_mega)
  u16* Xoh = Xkh;                                // over Xkh (dead after qkv_mega)

  // 1) numpy-exact fp32 thresholds
  np_leafsum_all<<<576, 256, 0, stream>>>(q_w, k_w, o_w, leaf);
  np_treemean3<<<3, 256, 0, stream>>>(leaf, th);

  // 2) quantize ternary weights -> bf16 + v_w bf16 cast (one launch)
  quant_split_all<<<2560, 256, 0, stream>>>(q_w, k_w, o_w, v_w, th, Wq, Wk, Wo, Vwh);

  // 3) RMSNorm(x) -> bf16 hi/lo (q,k gains) + raw-x bf16 (V path)
  rmsnorm_split6<<<Mc, 256, 0, stream>>>(x, q_g, k_g, Xqh, Xql, Xkh, Xkl, Xvh);

  // 4) fused Q+K+V projections: ONE launch, 768 blocks, all segments concurrent
  qkv_mega<<<768, 256, 0, stream>>>(Xqh, Xql, Wq, Xkh, Xkl, Wk, Xvh, Vwh,
                                    Qh, Ql, Kh, Kl, Vt);

  // 5) MFMA causal GQA attention v9 -> AO fp32
  attn_mfma9<<<dim3(32, 16, 1), 256, 0, stream>>>(Qh, Ql, Kh, Kl, Vt, qk_g, AO);

  // 6) output bitlinear: single-pass bf16 A
  rmsnorm_split6<<<Mc, 256, 0, stream>>>(AO, o_g, nullptr, Xoh, nullptr, nullptr, nullptr,
                                         nullptr);
  o_gemm<<<dim3(8, 64), 256, 0, stream>>>(Xoh, Wo, (float*)d_out);
}